// Round 6
// baseline (1252.885 us; speedup 1.0000x reference)
//
#include <hip/hip_runtime.h>
#include <hip/hip_bf16.h>
#include <cstdint>

typedef float  f32x4  __attribute__((ext_vector_type(4)));
typedef __bf16 bf16x8 __attribute__((ext_vector_type(8)));
typedef __bf16 bf16x4 __attribute__((ext_vector_type(4)));
typedef __bf16 bf16x2 __attribute__((ext_vector_type(2)));

#define AS1 __attribute__((address_space(1)))
#define AS3 __attribute__((address_space(3)))

static constexpr int D   = 4096;
static constexpr int SEQ = 2048;
static constexpr int MX  = 4224;   // padded rows: 4096 x-rows + 10 adapter + pad

__device__ __forceinline__ void gload_lds16(const void* g, void* l) {
  __builtin_amdgcn_global_load_lds((AS1 void*)(g), (AS3 void*)(l), 16, 0, 0);
}

__device__ __forceinline__ f32x4 mfma16(bf16x8 a, bf16x8 b, f32x4 c) {
  return __builtin_amdgcn_mfma_f32_16x16x32_bf16(a, b, c, 0, 0, 0);
}

// bijective XCD-chunked remap (m204): consecutive hardware dispatch ids
// round-robin XCDs; this gives each XCD a CONTIGUOUS chunk of logical ids.
__device__ __forceinline__ int xcd_chunk(int orig, int nwg) {
  int q = nwg >> 3, r = nwg & 7;
  int xcd = orig & 7, pos = orig >> 3;
  return (xcd < r ? xcd * (q + 1) : r * (q + 1) + (xcd - r) * q) + pos;
}

// ---------------------------------------------------------------------------
// transpose + cast: W (f32, K x N row-major) -> WT (bf16, N x K row-major)
__global__ __launch_bounds__(256) void transpose_cast(const float* __restrict__ W,
                                                      __bf16* __restrict__ WT) {
  __shared__ float tile[64][65];
  const int t  = threadIdx.x;
  const int r0 = blockIdx.x * 64;   // K index
  const int c0 = blockIdx.y * 64;   // N index
#pragma unroll
  for (int p = 0; p < 4; ++p) {
    int e = p * 1024 + t * 4;
    int row = e >> 6, col = e & 63;
    f32x4 v = *(const f32x4*)(W + (size_t)(r0 + row) * D + c0 + col);
#pragma unroll
    for (int i = 0; i < 4; ++i) tile[row][col + i] = v[i];
  }
  __syncthreads();
#pragma unroll
  for (int p = 0; p < 2; ++p) {
    int e = p * 2048 + t * 8;
    int orow = e >> 6, ocol = e & 63;
    bf16x8 o;
#pragma unroll
    for (int i = 0; i < 8; ++i) o[i] = (__bf16)tile[ocol + i][orow];
    *(bf16x8*)(WT + (size_t)(c0 + orow) * D + r0 + ocol) = o;
  }
}

// ---------------------------------------------------------------------------
// build xa (bf16, MX x D): rows 0..4095 = x, 4096..4105 = adapter, rest 0
__global__ __launch_bounds__(256) void build_xa(const float* __restrict__ x,
                                                const float* __restrict__ ad,
                                                __bf16* __restrict__ xa) {
  int idx = blockIdx.x * 256 + threadIdx.x;
  int e = idx * 4;
  int row = e >> 12, col = e & 4095;
  f32x4 v = {};
  if (row < 4096)      v = *(const f32x4*)(x + (size_t)row * D + col);
  else if (row < 4106) v = *(const f32x4*)(ad + (size_t)(row - 4096) * D + col);
  bf16x4 o;
#pragma unroll
  for (int i = 0; i < 4; ++i) o[i] = (__bf16)v[i];
  *(bf16x4*)(xa + (size_t)row * D + col) = o;
}

// ---------------------------------------------------------------------------
// GEMM: C[M x 4096] = A[M x 4096] * B, with B given transposed (BT: N x K).
// 128x128 tile, BK=64, 4 waves (2x2), 16x16x32 bf16 MFMA. m97 structure.
// Block mapping: XCD-chunked, m-fastest within chunk -> each XCD pins ~4
// B n-panels (4MB, fits its private L2) while all XCDs stream A K-slices
// in lockstep (served by L3).
template <bool F32OUT>
__global__ __launch_bounds__(256) void gemm_bt(const __bf16* __restrict__ A,
                                               const __bf16* __restrict__ BT,
                                               void* __restrict__ Cout) {
  __shared__ __bf16 As[128 * 64];
  __shared__ __bf16 Bs[128 * 64];
  const int tid = threadIdx.x;
  const int wv = tid >> 6, ln = tid & 63;
  const int lg = ln >> 4, lr = ln & 15;

  const int Mtiles = gridDim.x;
  const int nwg = Mtiles * gridDim.y;
  const int orig = blockIdx.y * Mtiles + blockIdx.x;
  const int wgid = xcd_chunk(orig, nwg);
  const int m0 = (wgid % Mtiles) * 128;
  const int n0 = (wgid / Mtiles) * 128;

  const int wm = (wv >> 1) * 64, wn = (wv & 1) * 64;

  f32x4 acc[4][4] = {};
  const __bf16* Ab = A + (size_t)m0 * D;
  const __bf16* Bb = BT + (size_t)n0 * D;

  for (int kt = 0; kt < D; kt += 64) {
#pragma unroll
    for (int j = 0; j < 4; ++j) {
      int c = wv * 256 + j * 64 + ln;
      int r = c >> 3, cb = c & 7;
      int sc = cb ^ (r & 7);
      gload_lds16(Ab + (size_t)r * D + kt + sc * 8, As + (wv * 256 + j * 64) * 8);
      gload_lds16(Bb + (size_t)r * D + kt + sc * 8, Bs + (wv * 256 + j * 64) * 8);
    }
    __syncthreads();
#pragma unroll
    for (int kk = 0; kk < 2; ++kk) {
      bf16x8 af[4], bfr[4];
#pragma unroll
      for (int i = 0; i < 4; ++i) {
        int ar = wm + i * 16 + lr;
        af[i] = *(const bf16x8*)(As + ar * 64 + (((kk * 4 + lg) ^ (ar & 7)) * 8));
        int br = wn + i * 16 + lr;
        bfr[i] = *(const bf16x8*)(Bs + br * 64 + (((kk * 4 + lg) ^ (br & 7)) * 8));
      }
#pragma unroll
      for (int mi = 0; mi < 4; ++mi)
#pragma unroll
        for (int ni = 0; ni < 4; ++ni)
          acc[mi][ni] = mfma16(af[mi], bfr[ni], acc[mi][ni]);
    }
    __syncthreads();
  }

#pragma unroll
  for (int mi = 0; mi < 4; ++mi)
#pragma unroll
    for (int ni = 0; ni < 4; ++ni)
#pragma unroll
      for (int j = 0; j < 4; ++j) {
        int row = m0 + wm + mi * 16 + lg * 4 + j;
        int col = n0 + wn + ni * 16 + lr;
        if constexpr (F32OUT)
          ((float*)Cout)[(size_t)row * D + col] = acc[mi][ni][j];
        else
          ((__bf16*)Cout)[(size_t)row * D + col] = (__bf16)acc[mi][ni][j];
      }
}

// ---------------------------------------------------------------------------
// RoPE in-place on q (4096 rows) and k (first 4096 rows). freqs are f32 tables.
__global__ __launch_bounds__(256) void rope_kernel(__bf16* __restrict__ q,
                                                   __bf16* __restrict__ k,
                                                   const float* __restrict__ fc,
                                                   const float* __restrict__ fs) {
  int row = blockIdx.x;
  __bf16* buf = blockIdx.y ? k : q;
  int t = threadIdx.x;
  int s = row & (SEQ - 1);
  int jb = (t & 7) * 8;
  const float* cp = fc + s * 64 + jb;
  const float* sp = fs + s * 64 + jb;
  __bf16* p = buf + (size_t)row * D + t * 16;
  bf16x8 v0 = *(const bf16x8*)p;
  bf16x8 v1 = *(const bf16x8*)(p + 8);
  bf16x8 o0, o1;
#pragma unroll
  for (int i = 0; i < 4; ++i) {
    float C = cp[i], Sn = sp[i];
    float re = (float)v0[2 * i], im = (float)v0[2 * i + 1];
    o0[2 * i]     = (__bf16)(re * C - im * Sn);
    o0[2 * i + 1] = (__bf16)(re * Sn + im * C);
  }
#pragma unroll
  for (int i = 0; i < 4; ++i) {
    float C = cp[4 + i], Sn = sp[4 + i];
    float re = (float)v1[2 * i], im = (float)v1[2 * i + 1];
    o1[2 * i]     = (__bf16)(re * C - im * Sn);
    o1[2 * i + 1] = (__bf16)(re * Sn + im * C);
  }
  *(bf16x8*)p = o0;
  *(bf16x8*)(p + 8) = o1;
}

// ---------------------------------------------------------------------------
// transpose V (MX x 4096 bf16) -> VT (4096 x MX bf16)
__global__ __launch_bounds__(256) void transpose_v(const __bf16* __restrict__ V,
                                                   __bf16* __restrict__ VT) {
  __shared__ __bf16 tile[64][72];
  const int t  = threadIdx.x;
  const int r0 = blockIdx.x * 64;   // V row (kv)
  const int c0 = blockIdx.y * 64;   // V col (dim)
#pragma unroll
  for (int p = 0; p < 2; ++p) {
    int e = p * 2048 + t * 8;
    int row = e >> 6, col = e & 63;
    bf16x8 v8 = *(const bf16x8*)(V + (size_t)(r0 + row) * D + c0 + col);
#pragma unroll
    for (int i = 0; i < 8; ++i) tile[row][col + i] = v8[i];
  }
  __syncthreads();
#pragma unroll
  for (int p = 0; p < 2; ++p) {
    int e = p * 2048 + t * 8;
    int orow = e >> 6, ocol = e & 63;
    bf16x8 o;
#pragma unroll
    for (int i = 0; i < 8; ++i) o[i] = tile[ocol + i][orow];
    *(bf16x8*)(VT + (size_t)(c0 + orow) * MX + r0 + ocol) = o;
  }
}

// ---------------------------------------------------------------------------
// Flash attention + adapter. Balanced pairs {qt, 15-qt}; K/V double-buffered
// LDS with counted vmcnt(8); swapped QK^T -> in-lane softmax. XCD-chunked
// block mapping groups 8 (h,b) heads per XCD (K/V working set 8MB).
// grid: 512 blocks (flat), 256 threads = 4 waves x 32 q-rows.
__global__ __launch_bounds__(256) void attn_kernel(const __bf16* __restrict__ Q,
                                                   const __bf16* __restrict__ K,
                                                   const __bf16* __restrict__ VT,
                                                   const float* __restrict__ gate,
                                                   __bf16* __restrict__ Out) {
  __shared__ __bf16 Ks[2][64 * 128];   // [kv][d] swizzled 16B chunks
  __shared__ __bf16 Vs[2][128 * 64];   // [d][kv] swizzled
  __shared__ __bf16 Ps[4][32 * 64];    // per-wave P

  const int tid = threadIdx.x;
  const int wv = tid >> 6, ln = tid & 63;
  const int lg = ln >> 4, lr = ln & 15;

  const int wgid = xcd_chunk(blockIdx.x, 512);
  const int px = wgid & 7;             // q-tile pair index
  const int hb = wgid >> 3;
  const int h = hb & 31, b = hb >> 5;

  const float scale = 0.08838834764831845f;   // 1/sqrt(128)
  const float g = tanhf(gate[h]);

  // stage kv-tile t into buffer buf: 8 VMEM ops per thread (4 K + 4 V)
  auto stage = [&](int t, int buf) {
    const int kv0 = t * 64;
#pragma unroll
    for (int j = 0; j < 4; ++j) {
      int c = wv * 256 + j * 64 + ln;
      int rk = c >> 4, sck = (c & 15) ^ (rk & 7);
      gload_lds16(K + (size_t)(b * SEQ + kv0 + rk) * D + h * 128 + sck * 8,
                  Ks[buf] + (wv * 256 + j * 64) * 8);
      int rv = c >> 3, scv = (c & 7) ^ (rv & 7);
      gload_lds16(VT + (size_t)(h * 128 + rv) * MX + b * SEQ + kv0 + scv * 8,
                  Vs[buf] + (wv * 256 + j * 64) * 8);
    }
  };

  auto run_supertile = [&](int qt) {
    const int q0 = qt * 128;
    const int qbase = b * SEQ + q0 + wv * 32;

    // Q fragments: [mi][kd]
    bf16x8 qf[2][4];
#pragma unroll
    for (int mi = 0; mi < 2; ++mi)
#pragma unroll
      for (int kd = 0; kd < 4; ++kd)
        qf[mi][kd] = *(const bf16x8*)(Q + (size_t)(qbase + mi * 16 + lr) * D +
                                      h * 128 + kd * 32 + lg * 8);

    f32x4 O[2][8] = {};
    float mI2[2], lI2[2];
#pragma unroll
    for (int mi = 0; mi < 2; ++mi) { mI2[mi] = -1e30f; lI2[mi] = 0.f; }

    const int ntiles = 2 * qt + 2;
    stage(0, 0);

    for (int t = 0; t < ntiles; ++t) {
      const int cur = t & 1;
      const int kv0 = t * 64;
      if (t + 1 < ntiles) {
        stage(t + 1, cur ^ 1);
        asm volatile("s_waitcnt vmcnt(8)" ::: "memory");  // tile t's loads done
      } else {
        asm volatile("s_waitcnt vmcnt(0)" ::: "memory");
      }
      __builtin_amdgcn_s_barrier();
      __builtin_amdgcn_sched_barrier(0);

      // ---- QK^T swapped: S[mi][nf] holds S^T fragment
      f32x4 S[2][4] = {};
      __builtin_amdgcn_s_setprio(1);
#pragma unroll
      for (int kd = 0; kd < 4; ++kd) {
        bf16x8 kf[4];
#pragma unroll
        for (int nf = 0; nf < 4; ++nf) {
          int kr = nf * 16 + lr;
          kf[nf] = *(const bf16x8*)(Ks[cur] + kr * 128 +
                                    (((kd * 4 + lg) ^ (kr & 7)) * 8));
        }
#pragma unroll
        for (int mi = 0; mi < 2; ++mi)
#pragma unroll
          for (int nf = 0; nf < 4; ++nf)
            S[mi][nf] = mfma16(kf[nf], qf[mi][kd], S[mi][nf]);
      }
      __builtin_amdgcn_s_setprio(0);

      // ---- in-lane softmax
      float r2[2]; int grew = 0;
#pragma unroll
      for (int mi = 0; mi < 2; ++mi) {
        const int qg = q0 + wv * 32 + mi * 16 + lr;
        float mo = mI2[mi];
        float mt = -3e38f;
#pragma unroll
        for (int nf = 0; nf < 4; ++nf)
#pragma unroll
          for (int j = 0; j < 4; ++j) {
            int kvg = kv0 + nf * 16 + lg * 4 + j;
            float s = S[mi][nf][j] * scale;
            s = (kvg > qg) ? -1e30f : s;
            S[mi][nf][j] = s;
            mt = fmaxf(mt, s);
          }
        mt = fmaxf(mt, __shfl_xor(mt, 16));
        mt = fmaxf(mt, __shfl_xor(mt, 32));
        float mn = fmaxf(mo, mt);
        float ps = 0.f;
#pragma unroll
        for (int nf = 0; nf < 4; ++nf)
#pragma unroll
          for (int j = 0; j < 4; ++j) {
            float p = __expf(S[mi][nf][j] - mn);
            S[mi][nf][j] = p;
            ps += p;
          }
        ps += __shfl_xor(ps, 16);
        ps += __shfl_xor(ps, 32);
        float r = __expf(mo - mn);
        lI2[mi] = lI2[mi] * r + ps;
        mI2[mi] = mn;
        r2[mi] = r;
        grew |= (mn > mo) ? 1 : 0;
      }
      if (__any(grew)) {
#pragma unroll
        for (int mi = 0; mi < 2; ++mi)
#pragma unroll
          for (int j = 0; j < 4; ++j) {
            float rj = __shfl(r2[mi], lg * 4 + j);
#pragma unroll
            for (int n = 0; n < 8; ++n) O[mi][n][j] *= rj;
          }
      }

      // ---- P -> bf16 pairs -> per-wave LDS (no barrier: same-wave)
#pragma unroll
      for (int mi = 0; mi < 2; ++mi) {
        int q = mi * 16 + lr;
#pragma unroll
        for (int nf = 0; nf < 4; ++nf)
#pragma unroll
          for (int jj = 0; jj < 2; ++jj) {
            int kv = nf * 16 + lg * 4 + 2 * jj;
            bf16x2 pk;
            pk[0] = (__bf16)S[mi][nf][2 * jj];
            pk[1] = (__bf16)S[mi][nf][2 * jj + 1];
            *(bf16x2*)(Ps[wv] + q * 64 + (((kv >> 3) ^ (q & 7)) * 8) + (kv & 7)) = pk;
          }
      }

      // ---- PV
      __builtin_amdgcn_s_setprio(1);
#pragma unroll
      for (int kkv = 0; kkv < 2; ++kkv) {
        bf16x8 pf[2];
#pragma unroll
        for (int mi = 0; mi < 2; ++mi) {
          int prw = mi * 16 + lr;
          pf[mi] = *(const bf16x8*)(Ps[wv] + prw * 64 +
                                    (((kkv * 4 + lg) ^ (prw & 7)) * 8));
        }
#pragma unroll
        for (int n = 0; n < 8; ++n) {
          int vr = n * 16 + lr;
          bf16x8 vf = *(const bf16x8*)(Vs[cur] + vr * 64 +
                                       (((kkv * 4 + lg) ^ (vr & 7)) * 8));
#pragma unroll
          for (int mi = 0; mi < 2; ++mi) O[mi][n] = mfma16(pf[mi], vf, O[mi][n]);
        }
      }
      __builtin_amdgcn_s_setprio(0);

      __builtin_amdgcn_s_barrier();          // buf reuse fence
      __builtin_amdgcn_sched_barrier(0);
    }

    // ---- normalize
#pragma unroll
    for (int mi = 0; mi < 2; ++mi) {
      float inv = 1.0f / lI2[mi];
#pragma unroll
      for (int j = 0; j < 4; ++j) {
        float invj = __shfl(inv, lg * 4 + j);
#pragma unroll
        for (int n = 0; n < 8; ++n) O[mi][n][j] *= invj;
      }
    }

    // ---- adapter branch (direct global fragments; 10 kv rows + zero pad)
    {
      f32x4 Sa[2] = {};
#pragma unroll
      for (int kd = 0; kd < 4; ++kd) {
        bf16x8 kfa = *(const bf16x8*)(K + (size_t)(2 * SEQ + lr) * D +
                                      h * 128 + kd * 32 + lg * 8);
#pragma unroll
        for (int mi = 0; mi < 2; ++mi) Sa[mi] = mfma16(kfa, qf[mi][kd], Sa[mi]);
      }
#pragma unroll
      for (int mi = 0; mi < 2; ++mi) {
        float mt = -3e38f;
#pragma unroll
        for (int j = 0; j < 4; ++j) {
          int kv = lg * 4 + j;
          float s = Sa[mi][j] * scale;
          s = (kv >= 10) ? -1e30f : s;
          Sa[mi][j] = s;
          mt = fmaxf(mt, s);
        }
        mt = fmaxf(mt, __shfl_xor(mt, 16));
        mt = fmaxf(mt, __shfl_xor(mt, 32));
        float ps = 0.f;
#pragma unroll
        for (int j = 0; j < 4; ++j) {
          float p = __expf(Sa[mi][j] - mt);
          Sa[mi][j] = p;
          ps += p;
        }
        ps += __shfl_xor(ps, 16);
        ps += __shfl_xor(ps, 32);
        float gs = g / ps;
        int q = mi * 16 + lr;
#pragma unroll
        for (int jj = 0; jj < 2; ++jj) {
          int kv = lg * 4 + 2 * jj;
          bf16x2 pk;
          pk[0] = (__bf16)(Sa[mi][2 * jj] * gs);
          pk[1] = (__bf16)(Sa[mi][2 * jj + 1] * gs);
          *(bf16x2*)(Ps[wv] + q * 64 + (((kv >> 3) ^ (q & 7)) * 8) + (kv & 7)) = pk;
          int kv2 = 16 + kv;
          bf16x2 z = {};
          *(bf16x2*)(Ps[wv] + q * 64 + (((kv2 >> 3) ^ (q & 7)) * 8) + (kv2 & 7)) = z;
        }
      }
      bf16x8 pfa[2];
#pragma unroll
      for (int mi = 0; mi < 2; ++mi) {
        int prw = mi * 16 + lr;
        pfa[mi] = *(const bf16x8*)(Ps[wv] + prw * 64 + ((lg ^ (prw & 7)) * 8));
      }
#pragma unroll
      for (int n = 0; n < 8; ++n) {
        bf16x8 vfa = *(const bf16x8*)(VT + (size_t)(h * 128 + n * 16 + lr) * MX +
                                      2 * SEQ + lg * 8);
#pragma unroll
        for (int mi = 0; mi < 2; ++mi) O[mi][n] = mfma16(pfa[mi], vfa, O[mi][n]);
      }
    }

    // ---- write out
#pragma unroll
    for (int mi = 0; mi < 2; ++mi)
#pragma unroll
      for (int n = 0; n < 8; ++n)
#pragma unroll
        for (int j = 0; j < 4; ++j)
          Out[(size_t)(qbase + mi * 16 + lg * 4 + j) * D + h * 128 + n * 16 + lr] =
              (__bf16)O[mi][n][j];
  };

  run_supertile(15 - px);   // heavy first
  run_supertile(px);
}

// ---------------------------------------------------------------------------
extern "C" void kernel_launch(void* const* d_in, const int* in_sizes, int n_in,
                              void* d_out, int out_size, void* d_ws, size_t ws_size,
                              hipStream_t stream) {
  const float* x    = (const float*)d_in[0];
  const float* wq   = (const float*)d_in[1];
  const float* wk   = (const float*)d_in[2];
  const float* wv   = (const float*)d_in[3];
  const float* wo   = (const float*)d_in[4];
  const float* gate = (const float*)d_in[5];
  const float* ad   = (const float*)d_in[6];
  const float* fc   = (const float*)d_in[7];
  const float* fs   = (const float*)d_in[8];

  const size_t WSZ = (size_t)D * D * 2;     // 33,554,432
  const size_t XSZ = (size_t)MX * D * 2;    // 34,603,008
  if (ws_size < 4 * WSZ + XSZ + WSZ + 3 * XSZ) return;  // 306,184,192 needed

  char* w = (char*)d_ws;
  size_t off = 0;
  auto alloc = [&](size_t sz) { void* p = w + off; off += sz; return p; };
  __bf16* wqT = (__bf16*)alloc(WSZ);
  __bf16* wkT = (__bf16*)alloc(WSZ);
  __bf16* wvT = (__bf16*)alloc(WSZ);
  __bf16* woT = (__bf16*)alloc(WSZ);
  __bf16* xa  = (__bf16*)alloc(XSZ);
  __bf16* qb  = (__bf16*)alloc(WSZ);
  __bf16* kb  = (__bf16*)alloc(XSZ);
  __bf16* vb  = (__bf16*)alloc(XSZ);
  __bf16* vT  = (__bf16*)alloc(XSZ);
  __bf16* attn = vb;   // vb dead after transpose_v; reuse as attention output

  dim3 blk(256);
  transpose_cast<<<dim3(64, 64), blk, 0, stream>>>(wq, wqT);
  transpose_cast<<<dim3(64, 64), blk, 0, stream>>>(wk, wkT);
  transpose_cast<<<dim3(64, 64), blk, 0, stream>>>(wv, wvT);
  transpose_cast<<<dim3(64, 64), blk, 0, stream>>>(wo, woT);
  build_xa<<<dim3(16896), blk, 0, stream>>>(x, ad, xa);

  gemm_bt<false><<<dim3(32, 32), blk, 0, stream>>>(xa, wqT, qb);
  gemm_bt<false><<<dim3(33, 32), blk, 0, stream>>>(xa, wkT, kb);
  gemm_bt<false><<<dim3(33, 32), blk, 0, stream>>>(xa, wvT, vb);

  rope_kernel<<<dim3(4096, 2), blk, 0, stream>>>(qb, kb, fc, fs);
  transpose_v<<<dim3(66, 64), blk, 0, stream>>>(vb, vT);

  attn_kernel<<<dim3(512), blk, 0, stream>>>(qb, kb, vT, gate, attn);

  gemm_bt<true><<<dim3(32, 32), blk, 0, stream>>>(attn, woT, d_out);
}

// Round 7
// 919.407 us; speedup vs baseline: 1.3627x; 1.3627x over previous
//
#include <hip/hip_runtime.h>
#include <hip/hip_bf16.h>
#include <cstdint>

typedef float  f32x4  __attribute__((ext_vector_type(4)));
typedef __bf16 bf16x8 __attribute__((ext_vector_type(8)));
typedef __bf16 bf16x4 __attribute__((ext_vector_type(4)));
typedef __bf16 bf16x2 __attribute__((ext_vector_type(2)));

#define AS1 __attribute__((address_space(1)))
#define AS3 __attribute__((address_space(3)))

static constexpr int D   = 4096;
static constexpr int SEQ = 2048;
static constexpr int MX  = 4224;   // padded rows: 4096 x-rows + 10 adapter + pad

__device__ __forceinline__ void gload_lds16(const void* g, void* l) {
  __builtin_amdgcn_global_load_lds((AS1 void*)(g), (AS3 void*)(l), 16, 0, 0);
}

__device__ __forceinline__ f32x4 mfma16(bf16x8 a, bf16x8 b, f32x4 c) {
  return __builtin_amdgcn_mfma_f32_16x16x32_bf16(a, b, c, 0, 0, 0);
}

// bijective XCD-chunked remap (m204) — used by attention only
__device__ __forceinline__ int xcd_chunk(int orig, int nwg) {
  int q = nwg >> 3, r = nwg & 7;
  int xcd = orig & 7, pos = orig >> 3;
  return (xcd < r ? xcd * (q + 1) : r * (q + 1) + (xcd - r) * q) + pos;
}

// ---------------------------------------------------------------------------
// transpose + cast: W (f32, K x N row-major) -> WT (bf16, N x K row-major)
__global__ __launch_bounds__(256) void transpose_cast(const float* __restrict__ W,
                                                      __bf16* __restrict__ WT) {
  __shared__ float tile[64][65];
  const int t  = threadIdx.x;
  const int r0 = blockIdx.x * 64;   // K index
  const int c0 = blockIdx.y * 64;   // N index
#pragma unroll
  for (int p = 0; p < 4; ++p) {
    int e = p * 1024 + t * 4;
    int row = e >> 6, col = e & 63;
    f32x4 v = *(const f32x4*)(W + (size_t)(r0 + row) * D + c0 + col);
#pragma unroll
    for (int i = 0; i < 4; ++i) tile[row][col + i] = v[i];
  }
  __syncthreads();
#pragma unroll
  for (int p = 0; p < 2; ++p) {
    int e = p * 2048 + t * 8;
    int orow = e >> 6, ocol = e & 63;
    bf16x8 o;
#pragma unroll
    for (int i = 0; i < 8; ++i) o[i] = (__bf16)tile[ocol + i][orow];
    *(bf16x8*)(WT + (size_t)(c0 + orow) * D + r0 + ocol) = o;
  }
}

// ---------------------------------------------------------------------------
// build xa (bf16, MX x D): rows 0..4095 = x, 4096..4105 = adapter, rest 0
__global__ __launch_bounds__(256) void build_xa(const float* __restrict__ x,
                                                const float* __restrict__ ad,
                                                __bf16* __restrict__ xa) {
  int idx = blockIdx.x * 256 + threadIdx.x;
  int e = idx * 4;
  int row = e >> 12, col = e & 4095;
  f32x4 v = {};
  if (row < 4096)      v = *(const f32x4*)(x + (size_t)row * D + col);
  else if (row < 4106) v = *(const f32x4*)(ad + (size_t)(row - 4096) * D + col);
  bf16x4 o;
#pragma unroll
  for (int i = 0; i < 4; ++i) o[i] = (__bf16)v[i];
  *(bf16x4*)(xa + (size_t)row * D + col) = o;
}

// ---------------------------------------------------------------------------
// Deep-pipelined GEMM: 256x256 tile, BK=32, 4-slot LDS ring (128KB), counted
// vmcnt(8) (staging 3 K-tiles ahead; never drains mid-loop). 512 threads =
// 8 waves (2M x 4N), per-wave C 128x64 = 8x4 16x16 frags, 32 MFMA/K-step.
// LDS page layout per (slot,matrix): [128 R][8 chunks of 16B], content
// (r,k) at R=r&127, chunk ch=(r>>7)*4+(k>>3) stored at cw=ch^(R&7)
// (0-bank-conflict proven swizzle; staging pre-swizzles the global source).
// Ring safety: stage(t+3) targets slot (t-1)&3 whose reads finished before
// the end-of-(t-1) barrier; per-wave vmcnt + barrier at tile end makes tile
// t+1's staged data globally visible before its ds_reads.
// MODE 0: fused QKV (bf16 out routed by n-panel, row-masked).
// MODE 1: single f32 output.
template <int MODE>
__global__ __launch_bounds__(512) void gemm256(const __bf16* __restrict__ A,
                                               const __bf16* __restrict__ BT,
                                               void* __restrict__ O0,
                                               void* __restrict__ O1,
                                               void* __restrict__ O2) {
  __shared__ __bf16 lds[4 * 2 * 8192];   // [slot][mat][8192 elems] = 128KB
  const int tid = threadIdx.x;
  const int wv = tid >> 6, ln = tid & 63;
  const int lg = ln >> 4, lr = ln & 15;
  const int m0 = blockIdx.x * 256, n0 = blockIdx.y * 256;
  const int wm = (wv >> 2) * 128, wn = (wv & 3) * 64;

  // stage K-tile t (32 k-cols) of A and B into ring slot t&3.
  // 4 gload_lds16 per thread per tile (2 issues x {A,B}).
  auto stage = [&](int t) {
    const int slot = t & 3;
    const int kt = t * 32;
#pragma unroll
    for (int i = 0; i < 2; ++i) {
      int R = i * 64 + (tid >> 3);
      int ch = (tid & 7) ^ (R & 7);
      int r = R + ((ch >> 2) << 7);
      int k0 = (ch & 3) << 3;
      gload_lds16(A + (size_t)(m0 + r) * 4096 + kt + k0,
                  lds + (slot * 2 + 0) * 8192 + i * 4096 + wv * 512);
      gload_lds16(BT + (size_t)(n0 + r) * 4096 + kt + k0,
                  lds + (slot * 2 + 1) * 8192 + i * 4096 + wv * 512);
    }
  };

  f32x4 acc[8][4] = {};

  stage(0); stage(1); stage(2);
  asm volatile("s_waitcnt vmcnt(8)" ::: "memory");   // tile 0 landed, 8 in flight
  __builtin_amdgcn_s_barrier();
  __builtin_amdgcn_sched_barrier(0);

  for (int t = 0; t < 128; ++t) {
    if (t + 3 < 128) stage(t + 3);

    const int slot = t & 3;
    const __bf16* pA = lds + (slot * 2 + 0) * 8192;
    const __bf16* pB = lds + (slot * 2 + 1) * 8192;
    bf16x8 a[8], b[4];
#pragma unroll
    for (int mi = 0; mi < 8; ++mi) {
      int r = wm + mi * 16 + lr;
      int R = r & 127;
      int cw = (((r >> 7) << 2) + lg) ^ (R & 7);
      a[mi] = *(const bf16x8*)(pA + R * 64 + cw * 8);
    }
#pragma unroll
    for (int ni = 0; ni < 4; ++ni) {
      int n = wn + ni * 16 + lr;
      int R = n & 127;
      int cw = (((n >> 7) << 2) + lg) ^ (R & 7);
      b[ni] = *(const bf16x8*)(pB + R * 64 + cw * 8);
    }

    __builtin_amdgcn_s_setprio(1);
#pragma unroll
    for (int mi = 0; mi < 8; ++mi)
#pragma unroll
      for (int ni = 0; ni < 4; ++ni)
        acc[mi][ni] = mfma16(a[mi], b[ni], acc[mi][ni]);
    __builtin_amdgcn_s_setprio(0);

    if (t < 127) {
      if (t < 125) asm volatile("s_waitcnt vmcnt(8)" ::: "memory");
      else         asm volatile("s_waitcnt vmcnt(0)" ::: "memory");
      __builtin_amdgcn_s_barrier();
      __builtin_amdgcn_sched_barrier(0);
    }
  }

  // epilogue
  if constexpr (MODE == 0) {
    const int sel = n0 >> 12;                 // 0=q, 1=k, 2=v
    __bf16* out = (sel == 0) ? (__bf16*)O0 : (sel == 1) ? (__bf16*)O1 : (__bf16*)O2;
    const int colb = n0 & 4095;
    const int Mmax = (sel == 0) ? 4096 : 4224;
#pragma unroll
    for (int mi = 0; mi < 8; ++mi)
#pragma unroll
      for (int j = 0; j < 4; ++j) {
        int row = m0 + wm + mi * 16 + lg * 4 + j;
        if (row < Mmax) {
#pragma unroll
          for (int ni = 0; ni < 4; ++ni) {
            int col = colb + wn + ni * 16 + lr;
            out[(size_t)row * 4096 + col] = (__bf16)acc[mi][ni][j];
          }
        }
      }
  } else {
    float* out = (float*)O0;
#pragma unroll
    for (int mi = 0; mi < 8; ++mi)
#pragma unroll
      for (int ni = 0; ni < 4; ++ni)
#pragma unroll
        for (int j = 0; j < 4; ++j) {
          int row = m0 + wm + mi * 16 + lg * 4 + j;
          int col = n0 + wn + ni * 16 + lr;
          out[(size_t)row * 4096 + col] = acc[mi][ni][j];
        }
  }
}

// ---------------------------------------------------------------------------
// RoPE in-place on q (4096 rows) and k (first 4096 rows). freqs are f32 tables.
__global__ __launch_bounds__(256) void rope_kernel(__bf16* __restrict__ q,
                                                   __bf16* __restrict__ k,
                                                   const float* __restrict__ fc,
                                                   const float* __restrict__ fs) {
  int row = blockIdx.x;
  __bf16* buf = blockIdx.y ? k : q;
  int t = threadIdx.x;
  int s = row & (SEQ - 1);
  int jb = (t & 7) * 8;
  const float* cp = fc + s * 64 + jb;
  const float* sp = fs + s * 64 + jb;
  __bf16* p = buf + (size_t)row * D + t * 16;
  bf16x8 v0 = *(const bf16x8*)p;
  bf16x8 v1 = *(const bf16x8*)(p + 8);
  bf16x8 o0, o1;
#pragma unroll
  for (int i = 0; i < 4; ++i) {
    float C = cp[i], Sn = sp[i];
    float re = (float)v0[2 * i], im = (float)v0[2 * i + 1];
    o0[2 * i]     = (__bf16)(re * C - im * Sn);
    o0[2 * i + 1] = (__bf16)(re * Sn + im * C);
  }
#pragma unroll
  for (int i = 0; i < 4; ++i) {
    float C = cp[4 + i], Sn = sp[4 + i];
    float re = (float)v1[2 * i], im = (float)v1[2 * i + 1];
    o1[2 * i]     = (__bf16)(re * C - im * Sn);
    o1[2 * i + 1] = (__bf16)(re * Sn + im * C);
  }
  *(bf16x8*)p = o0;
  *(bf16x8*)(p + 8) = o1;
}

// ---------------------------------------------------------------------------
// transpose V (MX x 4096 bf16) -> VT (4096 x MX bf16)
__global__ __launch_bounds__(256) void transpose_v(const __bf16* __restrict__ V,
                                                   __bf16* __restrict__ VT) {
  __shared__ __bf16 tile[64][72];
  const int t  = threadIdx.x;
  const int r0 = blockIdx.x * 64;   // V row (kv)
  const int c0 = blockIdx.y * 64;   // V col (dim)
#pragma unroll
  for (int p = 0; p < 2; ++p) {
    int e = p * 2048 + t * 8;
    int row = e >> 6, col = e & 63;
    bf16x8 v8 = *(const bf16x8*)(V + (size_t)(r0 + row) * D + c0 + col);
#pragma unroll
    for (int i = 0; i < 8; ++i) tile[row][col + i] = v8[i];
  }
  __syncthreads();
#pragma unroll
  for (int p = 0; p < 2; ++p) {
    int e = p * 2048 + t * 8;
    int orow = e >> 6, ocol = e & 63;
    bf16x8 o;
#pragma unroll
    for (int i = 0; i < 8; ++i) o[i] = tile[ocol + i][orow];
    *(bf16x8*)(VT + (size_t)(c0 + orow) * MX + r0 + ocol) = o;
  }
}

// ---------------------------------------------------------------------------
// Flash attention + adapter (unchanged from R6): balanced pairs {qt, 15-qt},
// K/V double-buffered LDS, counted vmcnt(8), swapped QK^T, in-lane softmax,
// XCD-chunked (h,b) grouping. 512 blocks, 256 threads.
__global__ __launch_bounds__(256) void attn_kernel(const __bf16* __restrict__ Q,
                                                   const __bf16* __restrict__ K,
                                                   const __bf16* __restrict__ VT,
                                                   const float* __restrict__ gate,
                                                   __bf16* __restrict__ Out) {
  __shared__ __bf16 Ks[2][64 * 128];
  __shared__ __bf16 Vs[2][128 * 64];
  __shared__ __bf16 Ps[4][32 * 64];

  const int tid = threadIdx.x;
  const int wv = tid >> 6, ln = tid & 63;
  const int lg = ln >> 4, lr = ln & 15;

  const int wgid = xcd_chunk(blockIdx.x, 512);
  const int px = wgid & 7;
  const int hb = wgid >> 3;
  const int h = hb & 31, b = hb >> 5;

  const float scale = 0.08838834764831845f;
  const float g = tanhf(gate[h]);

  auto stage = [&](int t, int buf) {
    const int kv0 = t * 64;
#pragma unroll
    for (int j = 0; j < 4; ++j) {
      int c = wv * 256 + j * 64 + ln;
      int rk = c >> 4, sck = (c & 15) ^ (rk & 7);
      gload_lds16(K + (size_t)(b * SEQ + kv0 + rk) * D + h * 128 + sck * 8,
                  Ks[buf] + (wv * 256 + j * 64) * 8);
      int rv = c >> 3, scv = (c & 7) ^ (rv & 7);
      gload_lds16(VT + (size_t)(h * 128 + rv) * MX + b * SEQ + kv0 + scv * 8,
                  Vs[buf] + (wv * 256 + j * 64) * 8);
    }
  };

  auto run_supertile = [&](int qt) {
    const int q0 = qt * 128;
    const int qbase = b * SEQ + q0 + wv * 32;

    bf16x8 qf[2][4];
#pragma unroll
    for (int mi = 0; mi < 2; ++mi)
#pragma unroll
      for (int kd = 0; kd < 4; ++kd)
        qf[mi][kd] = *(const bf16x8*)(Q + (size_t)(qbase + mi * 16 + lr) * D +
                                      h * 128 + kd * 32 + lg * 8);

    f32x4 O[2][8] = {};
    float mI2[2], lI2[2];
#pragma unroll
    for (int mi = 0; mi < 2; ++mi) { mI2[mi] = -1e30f; lI2[mi] = 0.f; }

    const int ntiles = 2 * qt + 2;
    stage(0, 0);

    for (int t = 0; t < ntiles; ++t) {
      const int cur = t & 1;
      const int kv0 = t * 64;
      if (t + 1 < ntiles) {
        stage(t + 1, cur ^ 1);
        asm volatile("s_waitcnt vmcnt(8)" ::: "memory");
      } else {
        asm volatile("s_waitcnt vmcnt(0)" ::: "memory");
      }
      __builtin_amdgcn_s_barrier();
      __builtin_amdgcn_sched_barrier(0);

      f32x4 S[2][4] = {};
      __builtin_amdgcn_s_setprio(1);
#pragma unroll
      for (int kd = 0; kd < 4; ++kd) {
        bf16x8 kf[4];
#pragma unroll
        for (int nf = 0; nf < 4; ++nf) {
          int kr = nf * 16 + lr;
          kf[nf] = *(const bf16x8*)(Ks[cur] + kr * 128 +
                                    (((kd * 4 + lg) ^ (kr & 7)) * 8));
        }
#pragma unroll
        for (int mi = 0; mi < 2; ++mi)
#pragma unroll
          for (int nf = 0; nf < 4; ++nf)
            S[mi][nf] = mfma16(kf[nf], qf[mi][kd], S[mi][nf]);
      }
      __builtin_amdgcn_s_setprio(0);

      float r2[2]; int grew = 0;
#pragma unroll
      for (int mi = 0; mi < 2; ++mi) {
        const int qg = q0 + wv * 32 + mi * 16 + lr;
        float mo = mI2[mi];
        float mt = -3e38f;
#pragma unroll
        for (int nf = 0; nf < 4; ++nf)
#pragma unroll
          for (int j = 0; j < 4; ++j) {
            int kvg = kv0 + nf * 16 + lg * 4 + j;
            float s = S[mi][nf][j] * scale;
            s = (kvg > qg) ? -1e30f : s;
            S[mi][nf][j] = s;
            mt = fmaxf(mt, s);
          }
        mt = fmaxf(mt, __shfl_xor(mt, 16));
        mt = fmaxf(mt, __shfl_xor(mt, 32));
        float mn = fmaxf(mo, mt);
        float ps = 0.f;
#pragma unroll
        for (int nf = 0; nf < 4; ++nf)
#pragma unroll
          for (int j = 0; j < 4; ++j) {
            float p = __expf(S[mi][nf][j] - mn);
            S[mi][nf][j] = p;
            ps += p;
          }
        ps += __shfl_xor(ps, 16);
        ps += __shfl_xor(ps, 32);
        float r = __expf(mo - mn);
        lI2[mi] = lI2[mi] * r + ps;
        mI2[mi] = mn;
        r2[mi] = r;
        grew |= (mn > mo) ? 1 : 0;
      }
      if (__any(grew)) {
#pragma unroll
        for (int mi = 0; mi < 2; ++mi)
#pragma unroll
          for (int j = 0; j < 4; ++j) {
            float rj = __shfl(r2[mi], lg * 4 + j);
#pragma unroll
            for (int n = 0; n < 8; ++n) O[mi][n][j] *= rj;
          }
      }

#pragma unroll
      for (int mi = 0; mi < 2; ++mi) {
        int q = mi * 16 + lr;
#pragma unroll
        for (int nf = 0; nf < 4; ++nf)
#pragma unroll
          for (int jj = 0; jj < 2; ++jj) {
            int kv = nf * 16 + lg * 4 + 2 * jj;
            bf16x2 pk;
            pk[0] = (__bf16)S[mi][nf][2 * jj];
            pk[1] = (__bf16)S[mi][nf][2 * jj + 1];
            *(bf16x2*)(Ps[wv] + q * 64 + (((kv >> 3) ^ (q & 7)) * 8) + (kv & 7)) = pk;
          }
      }

      __builtin_amdgcn_s_setprio(1);
#pragma unroll
      for (int kkv = 0; kkv < 2; ++kkv) {
        bf16x8 pf[2];
#pragma unroll
        for (int mi = 0; mi < 2; ++mi) {
          int prw = mi * 16 + lr;
          pf[mi] = *(const bf16x8*)(Ps[wv] + prw * 64 +
                                    (((kkv * 4 + lg) ^ (prw & 7)) * 8));
        }
#pragma unroll
        for (int n = 0; n < 8; ++n) {
          int vr = n * 16 + lr;
          bf16x8 vf = *(const bf16x8*)(Vs[cur] + vr * 64 +
                                       (((kkv * 4 + lg) ^ (vr & 7)) * 8));
#pragma unroll
          for (int mi = 0; mi < 2; ++mi) O[mi][n] = mfma16(pf[mi], vf, O[mi][n]);
        }
      }
      __builtin_amdgcn_s_setprio(0);

      __builtin_amdgcn_s_barrier();
      __builtin_amdgcn_sched_barrier(0);
    }

#pragma unroll
    for (int mi = 0; mi < 2; ++mi) {
      float inv = 1.0f / lI2[mi];
#pragma unroll
      for (int j = 0; j < 4; ++j) {
        float invj = __shfl(inv, lg * 4 + j);
#pragma unroll
        for (int n = 0; n < 8; ++n) O[mi][n][j] *= invj;
      }
    }

    {
      f32x4 Sa[2] = {};
#pragma unroll
      for (int kd = 0; kd < 4; ++kd) {
        bf16x8 kfa = *(const bf16x8*)(K + (size_t)(2 * SEQ + lr) * D +
                                      h * 128 + kd * 32 + lg * 8);
#pragma unroll
        for (int mi = 0; mi < 2; ++mi) Sa[mi] = mfma16(kfa, qf[mi][kd], Sa[mi]);
      }
#pragma unroll
      for (int mi = 0; mi < 2; ++mi) {
        float mt = -3e38f;
#pragma unroll
        for (int j = 0; j < 4; ++j) {
          int kv = lg * 4 + j;
          float s = Sa[mi][j] * scale;
          s = (kv >= 10) ? -1e30f : s;
          Sa[mi][j] = s;
          mt = fmaxf(mt, s);
        }
        mt = fmaxf(mt, __shfl_xor(mt, 16));
        mt = fmaxf(mt, __shfl_xor(mt, 32));
        float ps = 0.f;
#pragma unroll
        for (int j = 0; j < 4; ++j) {
          float p = __expf(Sa[mi][j] - mt);
          Sa[mi][j] = p;
          ps += p;
        }
        ps += __shfl_xor(ps, 16);
        ps += __shfl_xor(ps, 32);
        float gs = g / ps;
        int q = mi * 16 + lr;
#pragma unroll
        for (int jj = 0; jj < 2; ++jj) {
          int kv = lg * 4 + 2 * jj;
          bf16x2 pk;
          pk[0] = (__bf16)(Sa[mi][2 * jj] * gs);
          pk[1] = (__bf16)(Sa[mi][2 * jj + 1] * gs);
          *(bf16x2*)(Ps[wv] + q * 64 + (((kv >> 3) ^ (q & 7)) * 8) + (kv & 7)) = pk;
          int kv2 = 16 + kv;
          bf16x2 z = {};
          *(bf16x2*)(Ps[wv] + q * 64 + (((kv2 >> 3) ^ (q & 7)) * 8) + (kv2 & 7)) = z;
        }
      }
      bf16x8 pfa[2];
#pragma unroll
      for (int mi = 0; mi < 2; ++mi) {
        int prw = mi * 16 + lr;
        pfa[mi] = *(const bf16x8*)(Ps[wv] + prw * 64 + ((lg ^ (prw & 7)) * 8));
      }
#pragma unroll
      for (int n = 0; n < 8; ++n) {
        bf16x8 vfa = *(const bf16x8*)(VT + (size_t)(h * 128 + n * 16 + lr) * MX +
                                      2 * SEQ + lg * 8);
#pragma unroll
        for (int mi = 0; mi < 2; ++mi) O[mi][n] = mfma16(pfa[mi], vfa, O[mi][n]);
      }
    }

#pragma unroll
    for (int mi = 0; mi < 2; ++mi)
#pragma unroll
      for (int n = 0; n < 8; ++n)
#pragma unroll
        for (int j = 0; j < 4; ++j)
          Out[(size_t)(qbase + mi * 16 + lg * 4 + j) * D + h * 128 + n * 16 + lr] =
              (__bf16)O[mi][n][j];
  };

  run_supertile(15 - px);
  run_supertile(px);
}

// ---------------------------------------------------------------------------
extern "C" void kernel_launch(void* const* d_in, const int* in_sizes, int n_in,
                              void* d_out, int out_size, void* d_ws, size_t ws_size,
                              hipStream_t stream) {
  const float* x    = (const float*)d_in[0];
  const float* wq   = (const float*)d_in[1];
  const float* wk   = (const float*)d_in[2];
  const float* wv   = (const float*)d_in[3];
  const float* wo   = (const float*)d_in[4];
  const float* gate = (const float*)d_in[5];
  const float* ad   = (const float*)d_in[6];
  const float* fc   = (const float*)d_in[7];
  const float* fs   = (const float*)d_in[8];

  const size_t WSZ = (size_t)D * D * 2;     // 33,554,432
  const size_t XSZ = (size_t)MX * D * 2;    // 34,603,008
  if (ws_size < 4 * WSZ + XSZ + WSZ + 3 * XSZ) return;  // 306,184,192 needed

  char* w = (char*)d_ws;
  size_t off = 0;
  auto alloc = [&](size_t sz) { void* p = w + off; off += sz; return p; };
  __bf16* wqT = (__bf16*)alloc(WSZ);   // wqT/wkT/wvT contiguous = fused 12288xK B^T
  __bf16* wkT = (__bf16*)alloc(WSZ);
  __bf16* wvT = (__bf16*)alloc(WSZ);
  __bf16* woT = (__bf16*)alloc(WSZ);
  __bf16* xa  = (__bf16*)alloc(XSZ);
  __bf16* qb  = (__bf16*)alloc(WSZ);
  __bf16* kb  = (__bf16*)alloc(XSZ);
  __bf16* vb  = (__bf16*)alloc(XSZ);
  __bf16* vT  = (__bf16*)alloc(XSZ);
  __bf16* attn = vb;   // vb dead after transpose_v; reuse as attention output

  dim3 blk(256);
  transpose_cast<<<dim3(64, 64), blk, 0, stream>>>(wq, wqT);
  transpose_cast<<<dim3(64, 64), blk, 0, stream>>>(wk, wkT);
  transpose_cast<<<dim3(64, 64), blk, 0, stream>>>(wv, wvT);
  transpose_cast<<<dim3(64, 64), blk, 0, stream>>>(wo, woT);
  build_xa<<<dim3(16896), blk, 0, stream>>>(x, ad, xa);

  // fused QKV GEMM: M-tiles 17 (rows 4224..4351 read into qb-region garbage,
  // all such stores row-masked), N-tiles 48 (12288 fused cols).
  gemm256<0><<<dim3(17, 48), dim3(512), 0, stream>>>(xa, wqT, qb, kb, vb);

  rope_kernel<<<dim3(4096, 2), blk, 0, stream>>>(qb, kb, fc, fs);
  transpose_v<<<dim3(66, 64), blk, 0, stream>>>(vb, vT);

  attn_kernel<<<dim3(512), blk, 0, stream>>>(qb, kb, vT, gate, attn);

  gemm256<1><<<dim3(16, 16), dim3(512), 0, stream>>>(attn, woT, d_out, nullptr, nullptr);
}

// Round 8
// 913.027 us; speedup vs baseline: 1.3722x; 1.0070x over previous
//
#include <hip/hip_runtime.h>
#include <hip/hip_bf16.h>
#include <cstdint>

typedef float  f32x4  __attribute__((ext_vector_type(4)));
typedef __bf16 bf16x8 __attribute__((ext_vector_type(8)));
typedef __bf16 bf16x4 __attribute__((ext_vector_type(4)));
typedef __bf16 bf16x2 __attribute__((ext_vector_type(2)));

#define AS1 __attribute__((address_space(1)))
#define AS3 __attribute__((address_space(3)))

static constexpr int D   = 4096;
static constexpr int SEQ = 2048;
static constexpr int MX  = 4224;   // padded rows: 4096 x-rows + 10 adapter + pad

__device__ __forceinline__ void gload_lds16(const void* g, void* l) {
  __builtin_amdgcn_global_load_lds((AS1 void*)(g), (AS3 void*)(l), 16, 0, 0);
}

__device__ __forceinline__ f32x4 mfma16(bf16x8 a, bf16x8 b, f32x4 c) {
  return __builtin_amdgcn_mfma_f32_16x16x32_bf16(a, b, c, 0, 0, 0);
}

// bijective XCD-chunked remap (m204)
__device__ __forceinline__ int xcd_chunk(int orig, int nwg) {
  int q = nwg >> 3, r = nwg & 7;
  int xcd = orig & 7, pos = orig >> 3;
  return (xcd < r ? xcd * (q + 1) : r * (q + 1) + (xcd - r) * q) + pos;
}

// barrier that is also a compiler memory fence (raw builtin is not)
#define BARF() asm volatile("s_barrier" ::: "memory")

// ---------------------------------------------------------------------------
// transpose + cast: W (f32, K x N row-major) -> WT (bf16, N x K row-major)
__global__ __launch_bounds__(256) void transpose_cast(const float* __restrict__ W,
                                                      __bf16* __restrict__ WT) {
  __shared__ float tile[64][65];
  const int t  = threadIdx.x;
  const int r0 = blockIdx.x * 64;
  const int c0 = blockIdx.y * 64;
#pragma unroll
  for (int p = 0; p < 4; ++p) {
    int e = p * 1024 + t * 4;
    int row = e >> 6, col = e & 63;
    f32x4 v = *(const f32x4*)(W + (size_t)(r0 + row) * D + c0 + col);
#pragma unroll
    for (int i = 0; i < 4; ++i) tile[row][col + i] = v[i];
  }
  __syncthreads();
#pragma unroll
  for (int p = 0; p < 2; ++p) {
    int e = p * 2048 + t * 8;
    int orow = e >> 6, ocol = e & 63;
    bf16x8 o;
#pragma unroll
    for (int i = 0; i < 8; ++i) o[i] = (__bf16)tile[ocol + i][orow];
    *(bf16x8*)(WT + (size_t)(c0 + orow) * D + r0 + ocol) = o;
  }
}

// ---------------------------------------------------------------------------
// build xa (bf16, MX x D): rows 0..4095 = x, 4096..4105 = adapter, rest 0
__global__ __launch_bounds__(256) void build_xa(const float* __restrict__ x,
                                                const float* __restrict__ ad,
                                                __bf16* __restrict__ xa) {
  int idx = blockIdx.x * 256 + threadIdx.x;
  int e = idx * 4;
  int row = e >> 12, col = e & 4095;
  f32x4 v = {};
  if (row < 4096)      v = *(const f32x4*)(x + (size_t)row * D + col);
  else if (row < 4106) v = *(const f32x4*)(ad + (size_t)(row - 4096) * D + col);
  bf16x4 o;
#pragma unroll
  for (int i = 0; i < 4; ++i) o[i] = (__bf16)v[i];
  *(bf16x4*)(xa + (size_t)row * D + col) = o;
}

// ---------------------------------------------------------------------------
// Phase-scheduled GEMM: 256x256 tile, BK=64, double-buffered LDS (128KB),
// burst prefetch of tile t+1 at iter start + counted vmcnt(8); 4 compute
// phases per K-tile, each {ds_read new frags (snake quadrant order:
// 12/8/4/8), s_barrier, setprio(1), 16 MFMA, setprio(0)}; post-MFMA end
// barrier fences buffer reuse. 512 threads = 8 waves (2M x 4N), per-wave
// C = 128x64. Swizzle: chunk cw holds k-chunk cw^(r&7) (0-conflict, R7-
// proven); stage pre-swizzles the global source, LDS dst stays linear.
// MODE 0: fused QKV (bf16 out routed by n-panel, row-masked). MODE 1: f32.
template <int MODE>
__global__ __launch_bounds__(512, 2) void gemm256(const __bf16* __restrict__ A,
                                                  const __bf16* __restrict__ BT,
                                                  void* __restrict__ O0,
                                                  void* __restrict__ O1,
                                                  void* __restrict__ O2,
                                                  int Mt) {
  __shared__ __bf16 lds[65536];   // [2 buf][2 mat][2 half][128][64] = 128KB
  const int tid = threadIdx.x;
  const int wv = tid >> 6, ln = tid & 63;
  const int lg = ln >> 4, lr = ln & 15;

  const int nwg = gridDim.x;
  const int wgid = xcd_chunk(blockIdx.x, nwg);
  const int m0 = (wgid % Mt) * 256;
  const int n0 = (wgid / Mt) * 256;

  const int wm = (wv >> 2) * 128, wn = (wv & 3) * 64;

  // burst-stage K-tile t (A 256x64 + B 256x64) into buf t&1.
  // 8 gload_lds/thread; LDS dst linear in chunk id (wave-uniform base +
  // lane*16), global source pre-swizzled: slot cw <- k-chunk cw^(r&7).
  auto stage = [&](int t) {
    const int buf = t & 1;
    const int kt = t * 64;
#pragma unroll
    for (int i = 0; i < 8; ++i) {
      int c = i * 512 + tid;            // chunk id 0..4095
      int mat = c >> 11;                // 0=A, 1=B
      int cm = c & 2047;
      int r = cm >> 3;
      int ch = (cm & 7) ^ (r & 7);      // k-chunk content for this slot
      const __bf16* src = mat ? (BT + (size_t)(n0 + r) * 4096 + kt + ch * 8)
                              : (A  + (size_t)(m0 + r) * 4096 + kt + ch * 8);
      // wave-uniform LDS base (lane term implicit in HW lane*16)
      int base = buf * 32768 + mat * 16384 + ((i * 512 + wv * 64) & 2047) * 8;
      gload_lds16(src, lds + base);
    }
  };

  f32x4 acc[8][4] = {};
  bf16x8 aLo[4][2], aHi[4][2], bLo[2][2], bHi[2][2];

  stage(0);

  for (int t = 0; t < 64; ++t) {
    const int buf = t & 1;
    if (t + 1 < 64) {
      stage(t + 1);
      asm volatile("s_waitcnt vmcnt(8)" ::: "memory");   // tile t landed (mine)
    } else {
      asm volatile("s_waitcnt vmcnt(0)" ::: "memory");
    }
    BARF();   // tile-ready: ALL waves' stage loads for tile t landed

    const __bf16* pA = lds + buf * 32768;
    const __bf16* pB = lds + buf * 32768 + 16384;

    auto rdA = [&](int mi, int kk) -> bf16x8 {
      int r = wm + mi * 16 + lr;
      int R = r & 127;
      int cw = (kk * 4 + lg) ^ (R & 7);
      return *(const bf16x8*)(pA + (r >> 7) * 8192 + R * 64 + cw * 8);
    };
    auto rdB = [&](int ni, int kk) -> bf16x8 {
      int n = wn + ni * 16 + lr;
      int R = n & 127;
      int cw = (kk * 4 + lg) ^ (R & 7);
      return *(const bf16x8*)(pB + (n >> 7) * 8192 + R * 64 + cw * 8);
    };

    // ---- P0: quadrant (mi 0-3, ni 0-1)
#pragma unroll
    for (int mi = 0; mi < 4; ++mi)
#pragma unroll
      for (int kk = 0; kk < 2; ++kk) aLo[mi][kk] = rdA(mi, kk);
#pragma unroll
    for (int ni = 0; ni < 2; ++ni)
#pragma unroll
      for (int kk = 0; kk < 2; ++kk) bLo[ni][kk] = rdB(ni, kk);
    BARF();
    __builtin_amdgcn_s_setprio(1);
#pragma unroll
    for (int kk = 0; kk < 2; ++kk)
#pragma unroll
      for (int mi = 0; mi < 4; ++mi)
#pragma unroll
        for (int ni = 0; ni < 2; ++ni)
          acc[mi][ni] = mfma16(aLo[mi][kk], bLo[ni][kk], acc[mi][ni]);
    __builtin_amdgcn_s_setprio(0);

    // ---- P1: quadrant (mi 4-7, ni 0-1), reuse bLo
#pragma unroll
    for (int mi = 0; mi < 4; ++mi)
#pragma unroll
      for (int kk = 0; kk < 2; ++kk) aHi[mi][kk] = rdA(mi + 4, kk);
    BARF();
    __builtin_amdgcn_s_setprio(1);
#pragma unroll
    for (int kk = 0; kk < 2; ++kk)
#pragma unroll
      for (int mi = 0; mi < 4; ++mi)
#pragma unroll
        for (int ni = 0; ni < 2; ++ni)
          acc[mi + 4][ni] = mfma16(aHi[mi][kk], bLo[ni][kk], acc[mi + 4][ni]);
    __builtin_amdgcn_s_setprio(0);

    // ---- P2: quadrant (mi 4-7, ni 2-3), reuse aHi
#pragma unroll
    for (int ni = 0; ni < 2; ++ni)
#pragma unroll
      for (int kk = 0; kk < 2; ++kk) bHi[ni][kk] = rdB(ni + 2, kk);
    BARF();
    __builtin_amdgcn_s_setprio(1);
#pragma unroll
    for (int kk = 0; kk < 2; ++kk)
#pragma unroll
      for (int mi = 0; mi < 4; ++mi)
#pragma unroll
        for (int ni = 0; ni < 2; ++ni)
          acc[mi + 4][ni + 2] = mfma16(aHi[mi][kk], bHi[ni][kk], acc[mi + 4][ni + 2]);
    __builtin_amdgcn_s_setprio(0);

    // ---- P3: quadrant (mi 0-3, ni 2-3), re-read aLo
#pragma unroll
    for (int mi = 0; mi < 4; ++mi)
#pragma unroll
      for (int kk = 0; kk < 2; ++kk) aLo[mi][kk] = rdA(mi, kk);
    BARF();
    __builtin_amdgcn_s_setprio(1);
#pragma unroll
    for (int kk = 0; kk < 2; ++kk)
#pragma unroll
      for (int mi = 0; mi < 4; ++mi)
#pragma unroll
        for (int ni = 0; ni < 2; ++ni)
          acc[mi][ni + 2] = mfma16(aLo[mi][kk], bHi[ni][kk], acc[mi][ni + 2]);
    __builtin_amdgcn_s_setprio(0);

    BARF();   // end: all waves' reads of buf complete -> next burst may overwrite
  }

  // epilogue
  if constexpr (MODE == 0) {
    const int sel = n0 >> 12;                 // 0=q, 1=k, 2=v
    __bf16* out = (sel == 0) ? (__bf16*)O0 : (sel == 1) ? (__bf16*)O1 : (__bf16*)O2;
    const int colb = n0 & 4095;
    const int Mmax = (sel == 0) ? 4096 : 4224;
#pragma unroll
    for (int mi = 0; mi < 8; ++mi)
#pragma unroll
      for (int j = 0; j < 4; ++j) {
        int row = m0 + wm + mi * 16 + lg * 4 + j;
        if (row < Mmax) {
#pragma unroll
          for (int ni = 0; ni < 4; ++ni) {
            int col = colb + wn + ni * 16 + lr;
            out[(size_t)row * 4096 + col] = (__bf16)acc[mi][ni][j];
          }
        }
      }
  } else {
    float* out = (float*)O0;
#pragma unroll
    for (int mi = 0; mi < 8; ++mi)
#pragma unroll
      for (int ni = 0; ni < 4; ++ni)
#pragma unroll
        for (int j = 0; j < 4; ++j) {
          int row = m0 + wm + mi * 16 + lg * 4 + j;
          int col = n0 + wn + ni * 16 + lr;
          out[(size_t)row * 4096 + col] = acc[mi][ni][j];
        }
  }
}

// ---------------------------------------------------------------------------
// RoPE in-place on q (4096 rows) and k (first 4096 rows).
__global__ __launch_bounds__(256) void rope_kernel(__bf16* __restrict__ q,
                                                   __bf16* __restrict__ k,
                                                   const float* __restrict__ fc,
                                                   const float* __restrict__ fs) {
  int row = blockIdx.x;
  __bf16* buf = blockIdx.y ? k : q;
  int t = threadIdx.x;
  int s = row & (SEQ - 1);
  int jb = (t & 7) * 8;
  const float* cp = fc + s * 64 + jb;
  const float* sp = fs + s * 64 + jb;
  __bf16* p = buf + (size_t)row * D + t * 16;
  bf16x8 v0 = *(const bf16x8*)p;
  bf16x8 v1 = *(const bf16x8*)(p + 8);
  bf16x8 o0, o1;
#pragma unroll
  for (int i = 0; i < 4; ++i) {
    float C = cp[i], Sn = sp[i];
    float re = (float)v0[2 * i], im = (float)v0[2 * i + 1];
    o0[2 * i]     = (__bf16)(re * C - im * Sn);
    o0[2 * i + 1] = (__bf16)(re * Sn + im * C);
  }
#pragma unroll
  for (int i = 0; i < 4; ++i) {
    float C = cp[4 + i], Sn = sp[4 + i];
    float re = (float)v1[2 * i], im = (float)v1[2 * i + 1];
    o1[2 * i]     = (__bf16)(re * C - im * Sn);
    o1[2 * i + 1] = (__bf16)(re * Sn + im * C);
  }
  *(bf16x8*)p = o0;
  *(bf16x8*)(p + 8) = o1;
}

// ---------------------------------------------------------------------------
// transpose V (MX x 4096 bf16) -> VT (4096 x MX bf16)
__global__ __launch_bounds__(256) void transpose_v(const __bf16* __restrict__ V,
                                                   __bf16* __restrict__ VT) {
  __shared__ __bf16 tile[64][72];
  const int t  = threadIdx.x;
  const int r0 = blockIdx.x * 64;
  const int c0 = blockIdx.y * 64;
#pragma unroll
  for (int p = 0; p < 2; ++p) {
    int e = p * 2048 + t * 8;
    int row = e >> 6, col = e & 63;
    bf16x8 v8 = *(const bf16x8*)(V + (size_t)(r0 + row) * D + c0 + col);
#pragma unroll
    for (int i = 0; i < 8; ++i) tile[row][col + i] = v8[i];
  }
  __syncthreads();
#pragma unroll
  for (int p = 0; p < 2; ++p) {
    int e = p * 2048 + t * 8;
    int orow = e >> 6, ocol = e & 63;
    bf16x8 o;
#pragma unroll
    for (int i = 0; i < 8; ++i) o[i] = tile[ocol + i][orow];
    *(bf16x8*)(VT + (size_t)(c0 + orow) * MX + r0 + ocol) = o;
  }
}

// ---------------------------------------------------------------------------
// Flash attention + adapter (unchanged from R6/R7).
__global__ __launch_bounds__(256) void attn_kernel(const __bf16* __restrict__ Q,
                                                   const __bf16* __restrict__ K,
                                                   const __bf16* __restrict__ VT,
                                                   const float* __restrict__ gate,
                                                   __bf16* __restrict__ Out) {
  __shared__ __bf16 Ks[2][64 * 128];
  __shared__ __bf16 Vs[2][128 * 64];
  __shared__ __bf16 Ps[4][32 * 64];

  const int tid = threadIdx.x;
  const int wv = tid >> 6, ln = tid & 63;
  const int lg = ln >> 4, lr = ln & 15;

  const int wgid = xcd_chunk(blockIdx.x, 512);
  const int px = wgid & 7;
  const int hb = wgid >> 3;
  const int h = hb & 31, b = hb >> 5;

  const float scale = 0.08838834764831845f;
  const float g = tanhf(gate[h]);

  auto stage = [&](int t, int buf) {
    const int kv0 = t * 64;
#pragma unroll
    for (int j = 0; j < 4; ++j) {
      int c = wv * 256 + j * 64 + ln;
      int rk = c >> 4, sck = (c & 15) ^ (rk & 7);
      gload_lds16(K + (size_t)(b * SEQ + kv0 + rk) * D + h * 128 + sck * 8,
                  Ks[buf] + (wv * 256 + j * 64) * 8);
      int rv = c >> 3, scv = (c & 7) ^ (rv & 7);
      gload_lds16(VT + (size_t)(h * 128 + rv) * MX + b * SEQ + kv0 + scv * 8,
                  Vs[buf] + (wv * 256 + j * 64) * 8);
    }
  };

  auto run_supertile = [&](int qt) {
    const int q0 = qt * 128;
    const int qbase = b * SEQ + q0 + wv * 32;

    bf16x8 qf[2][4];
#pragma unroll
    for (int mi = 0; mi < 2; ++mi)
#pragma unroll
      for (int kd = 0; kd < 4; ++kd)
        qf[mi][kd] = *(const bf16x8*)(Q + (size_t)(qbase + mi * 16 + lr) * D +
                                      h * 128 + kd * 32 + lg * 8);

    f32x4 O[2][8] = {};
    float mI2[2], lI2[2];
#pragma unroll
    for (int mi = 0; mi < 2; ++mi) { mI2[mi] = -1e30f; lI2[mi] = 0.f; }

    const int ntiles = 2 * qt + 2;
    stage(0, 0);

    for (int t = 0; t < ntiles; ++t) {
      const int cur = t & 1;
      const int kv0 = t * 64;
      if (t + 1 < ntiles) {
        stage(t + 1, cur ^ 1);
        asm volatile("s_waitcnt vmcnt(8)" ::: "memory");
      } else {
        asm volatile("s_waitcnt vmcnt(0)" ::: "memory");
      }
      __builtin_amdgcn_s_barrier();
      __builtin_amdgcn_sched_barrier(0);

      f32x4 S[2][4] = {};
      __builtin_amdgcn_s_setprio(1);
#pragma unroll
      for (int kd = 0; kd < 4; ++kd) {
        bf16x8 kf[4];
#pragma unroll
        for (int nf = 0; nf < 4; ++nf) {
          int kr = nf * 16 + lr;
          kf[nf] = *(const bf16x8*)(Ks[cur] + kr * 128 +
                                    (((kd * 4 + lg) ^ (kr & 7)) * 8));
        }
#pragma unroll
        for (int mi = 0; mi < 2; ++mi)
#pragma unroll
          for (int nf = 0; nf < 4; ++nf)
            S[mi][nf] = mfma16(kf[nf], qf[mi][kd], S[mi][nf]);
      }
      __builtin_amdgcn_s_setprio(0);

      float r2[2]; int grew = 0;
#pragma unroll
      for (int mi = 0; mi < 2; ++mi) {
        const int qg = q0 + wv * 32 + mi * 16 + lr;
        float mo = mI2[mi];
        float mt = -3e38f;
#pragma unroll
        for (int nf = 0; nf < 4; ++nf)
#pragma unroll
          for (int j = 0; j < 4; ++j) {
            int kvg = kv0 + nf * 16 + lg * 4 + j;
            float s = S[mi][nf][j] * scale;
            s = (kvg > qg) ? -1e30f : s;
            S[mi][nf][j] = s;
            mt = fmaxf(mt, s);
          }
        mt = fmaxf(mt, __shfl_xor(mt, 16));
        mt = fmaxf(mt, __shfl_xor(mt, 32));
        float mn = fmaxf(mo, mt);
        float ps = 0.f;
#pragma unroll
        for (int nf = 0; nf < 4; ++nf)
#pragma unroll
          for (int j = 0; j < 4; ++j) {
            float p = __expf(S[mi][nf][j] - mn);
            S[mi][nf][j] = p;
            ps += p;
          }
        ps += __shfl_xor(ps, 16);
        ps += __shfl_xor(ps, 32);
        float r = __expf(mo - mn);
        lI2[mi] = lI2[mi] * r + ps;
        mI2[mi] = mn;
        r2[mi] = r;
        grew |= (mn > mo) ? 1 : 0;
      }
      if (__any(grew)) {
#pragma unroll
        for (int mi = 0; mi < 2; ++mi)
#pragma unroll
          for (int j = 0; j < 4; ++j) {
            float rj = __shfl(r2[mi], lg * 4 + j);
#pragma unroll
            for (int n = 0; n < 8; ++n) O[mi][n][j] *= rj;
          }
      }

#pragma unroll
      for (int mi = 0; mi < 2; ++mi) {
        int q = mi * 16 + lr;
#pragma unroll
        for (int nf = 0; nf < 4; ++nf)
#pragma unroll
          for (int jj = 0; jj < 2; ++jj) {
            int kv = nf * 16 + lg * 4 + 2 * jj;
            bf16x2 pk;
            pk[0] = (__bf16)S[mi][nf][2 * jj];
            pk[1] = (__bf16)S[mi][nf][2 * jj + 1];
            *(bf16x2*)(Ps[wv] + q * 64 + (((kv >> 3) ^ (q & 7)) * 8) + (kv & 7)) = pk;
          }
      }

      __builtin_amdgcn_s_setprio(1);
#pragma unroll
      for (int kkv = 0; kkv < 2; ++kkv) {
        bf16x8 pf[2];
#pragma unroll
        for (int mi = 0; mi < 2; ++mi) {
          int prw = mi * 16 + lr;
          pf[mi] = *(const bf16x8*)(Ps[wv] + prw * 64 +
                                    (((kkv * 4 + lg) ^ (prw & 7)) * 8));
        }
#pragma unroll
        for (int n = 0; n < 8; ++n) {
          int vr = n * 16 + lr;
          bf16x8 vf = *(const bf16x8*)(Vs[cur] + vr * 64 +
                                       (((kkv * 4 + lg) ^ (vr & 7)) * 8));
#pragma unroll
          for (int mi = 0; mi < 2; ++mi) O[mi][n] = mfma16(pf[mi], vf, O[mi][n]);
        }
      }
      __builtin_amdgcn_s_setprio(0);

      __builtin_amdgcn_s_barrier();
      __builtin_amdgcn_sched_barrier(0);
    }

#pragma unroll
    for (int mi = 0; mi < 2; ++mi) {
      float inv = 1.0f / lI2[mi];
#pragma unroll
      for (int j = 0; j < 4; ++j) {
        float invj = __shfl(inv, lg * 4 + j);
#pragma unroll
        for (int n = 0; n < 8; ++n) O[mi][n][j] *= invj;
      }
    }

    {
      f32x4 Sa[2] = {};
#pragma unroll
      for (int kd = 0; kd < 4; ++kd) {
        bf16x8 kfa = *(const bf16x8*)(K + (size_t)(2 * SEQ + lr) * D +
                                      h * 128 + kd * 32 + lg * 8);
#pragma unroll
        for (int mi = 0; mi < 2; ++mi) Sa[mi] = mfma16(kfa, qf[mi][kd], Sa[mi]);
      }
#pragma unroll
      for (int mi = 0; mi < 2; ++mi) {
        float mt = -3e38f;
#pragma unroll
        for (int j = 0; j < 4; ++j) {
          int kv = lg * 4 + j;
          float s = Sa[mi][j] * scale;
          s = (kv >= 10) ? -1e30f : s;
          Sa[mi][j] = s;
          mt = fmaxf(mt, s);
        }
        mt = fmaxf(mt, __shfl_xor(mt, 16));
        mt = fmaxf(mt, __shfl_xor(mt, 32));
        float ps = 0.f;
#pragma unroll
        for (int j = 0; j < 4; ++j) {
          float p = __expf(Sa[mi][j] - mt);
          Sa[mi][j] = p;
          ps += p;
        }
        ps += __shfl_xor(ps, 16);
        ps += __shfl_xor(ps, 32);
        float gs = g / ps;
        int q = mi * 16 + lr;
#pragma unroll
        for (int jj = 0; jj < 2; ++jj) {
          int kv = lg * 4 + 2 * jj;
          bf16x2 pk;
          pk[0] = (__bf16)(Sa[mi][2 * jj] * gs);
          pk[1] = (__bf16)(Sa[mi][2 * jj + 1] * gs);
          *(bf16x2*)(Ps[wv] + q * 64 + (((kv >> 3) ^ (q & 7)) * 8) + (kv & 7)) = pk;
          int kv2 = 16 + kv;
          bf16x2 z = {};
          *(bf16x2*)(Ps[wv] + q * 64 + (((kv2 >> 3) ^ (q & 7)) * 8) + (kv2 & 7)) = z;
        }
      }
      bf16x8 pfa[2];
#pragma unroll
      for (int mi = 0; mi < 2; ++mi) {
        int prw = mi * 16 + lr;
        pfa[mi] = *(const bf16x8*)(Ps[wv] + prw * 64 + ((lg ^ (prw & 7)) * 8));
      }
#pragma unroll
      for (int n = 0; n < 8; ++n) {
        bf16x8 vfa = *(const bf16x8*)(VT + (size_t)(h * 128 + n * 16 + lr) * MX +
                                      2 * SEQ + lg * 8);
#pragma unroll
        for (int mi = 0; mi < 2; ++mi) O[mi][n] = mfma16(pfa[mi], vfa, O[mi][n]);
      }
    }

#pragma unroll
    for (int mi = 0; mi < 2; ++mi)
#pragma unroll
      for (int n = 0; n < 8; ++n)
#pragma unroll
        for (int j = 0; j < 4; ++j)
          Out[(size_t)(qbase + mi * 16 + lg * 4 + j) * D + h * 128 + n * 16 + lr] =
              (__bf16)O[mi][n][j];
  };

  run_supertile(15 - px);
  run_supertile(px);
}

// ---------------------------------------------------------------------------
extern "C" void kernel_launch(void* const* d_in, const int* in_sizes, int n_in,
                              void* d_out, int out_size, void* d_ws, size_t ws_size,
                              hipStream_t stream) {
  const float* x    = (const float*)d_in[0];
  const float* wq   = (const float*)d_in[1];
  const float* wk   = (const float*)d_in[2];
  const float* wv   = (const float*)d_in[3];
  const float* wo   = (const float*)d_in[4];
  const float* gate = (const float*)d_in[5];
  const float* ad   = (const float*)d_in[6];
  const float* fc   = (const float*)d_in[7];
  const float* fs   = (const float*)d_in[8];

  const size_t WSZ = (size_t)D * D * 2;     // 33,554,432
  const size_t XSZ = (size_t)MX * D * 2;    // 34,603,008
  if (ws_size < 4 * WSZ + XSZ + WSZ + 3 * XSZ) return;  // 306,184,192 needed

  char* w = (char*)d_ws;
  size_t off = 0;
  auto alloc = [&](size_t sz) { void* p = w + off; off += sz; return p; };
  __bf16* wqT = (__bf16*)alloc(WSZ);   // wqT/wkT/wvT contiguous = fused 12288xK B^T
  __bf16* wkT = (__bf16*)alloc(WSZ);
  __bf16* wvT = (__bf16*)alloc(WSZ);
  __bf16* woT = (__bf16*)alloc(WSZ);
  __bf16* xa  = (__bf16*)alloc(XSZ);
  __bf16* qb  = (__bf16*)alloc(WSZ);
  __bf16* kb  = (__bf16*)alloc(XSZ);
  __bf16* vb  = (__bf16*)alloc(XSZ);
  __bf16* vT  = (__bf16*)alloc(XSZ);
  __bf16* attn = vb;   // vb dead after transpose_v; reuse as attention output

  dim3 blk(256);
  transpose_cast<<<dim3(64, 64), blk, 0, stream>>>(wq, wqT);
  transpose_cast<<<dim3(64, 64), blk, 0, stream>>>(wk, wkT);
  transpose_cast<<<dim3(64, 64), blk, 0, stream>>>(wv, wvT);
  transpose_cast<<<dim3(64, 64), blk, 0, stream>>>(wo, woT);
  build_xa<<<dim3(16896), blk, 0, stream>>>(x, ad, xa);

  // fused QKV GEMM: 17 M-tiles x 48 N-tiles = 816 blocks (816 % 8 == 0).
  gemm256<0><<<dim3(17 * 48), dim3(512), 0, stream>>>(xa, wqT, qb, kb, vb, 17);

  rope_kernel<<<dim3(4096, 2), blk, 0, stream>>>(qb, kb, fc, fs);
  transpose_v<<<dim3(66, 64), blk, 0, stream>>>(vb, vT);

  attn_kernel<<<dim3(512), blk, 0, stream>>>(qb, kb, vT, gate, attn);

  gemm256<1><<<dim3(16 * 16), dim3(512), 0, stream>>>(attn, woT, d_out, nullptr, nullptr, 16);
}

// Round 10
// 897.979 us; speedup vs baseline: 1.3952x; 1.0168x over previous
//
#include <hip/hip_runtime.h>
#include <hip/hip_bf16.h>
#include <cstdint>

typedef float  f32x4  __attribute__((ext_vector_type(4)));
typedef __bf16 bf16x8 __attribute__((ext_vector_type(8)));
typedef __bf16 bf16x4 __attribute__((ext_vector_type(4)));
typedef __bf16 bf16x2 __attribute__((ext_vector_type(2)));

#define AS1 __attribute__((address_space(1)))
#define AS3 __attribute__((address_space(3)))

static constexpr int D   = 4096;
static constexpr int SEQ = 2048;
static constexpr int MX  = 4224;   // padded rows: 4096 x-rows + 10 adapter + pad

__device__ __forceinline__ void gload_lds16(const void* g, void* l) {
  __builtin_amdgcn_global_load_lds((AS1 void*)(g), (AS3 void*)(l), 16, 0, 0);
}

__device__ __forceinline__ f32x4 mfma16(bf16x8 a, bf16x8 b, f32x4 c) {
  return __builtin_amdgcn_mfma_f32_16x16x32_bf16(a, b, c, 0, 0, 0);
}

// bijective XCD-chunked remap (m204)
__device__ __forceinline__ int xcd_chunk(int orig, int nwg) {
  int q = nwg >> 3, r = nwg & 7;
  int xcd = orig & 7, pos = orig >> 3;
  return (xcd < r ? xcd * (q + 1) : r * (q + 1) + (xcd - r) * q) + pos;
}

// barrier that is also a compiler memory fence
#define BARF() asm volatile("s_barrier" ::: "memory")

// ---------------------------------------------------------------------------
// transpose + cast: W (f32, K x N row-major) -> WT (bf16, N x K row-major)
__global__ __launch_bounds__(256) void transpose_cast(const float* __restrict__ W,
                                                      __bf16* __restrict__ WT) {
  __shared__ float tile[64][65];
  const int t  = threadIdx.x;
  const int r0 = blockIdx.x * 64;
  const int c0 = blockIdx.y * 64;
#pragma unroll
  for (int p = 0; p < 4; ++p) {
    int e = p * 1024 + t * 4;
    int row = e >> 6, col = e & 63;
    f32x4 v = *(const f32x4*)(W + (size_t)(r0 + row) * D + c0 + col);
#pragma unroll
    for (int i = 0; i < 4; ++i) tile[row][col + i] = v[i];
  }
  __syncthreads();
#pragma unroll
  for (int p = 0; p < 2; ++p) {
    int e = p * 2048 + t * 8;
    int orow = e >> 6, ocol = e & 63;
    bf16x8 o;
#pragma unroll
    for (int i = 0; i < 8; ++i) o[i] = (__bf16)tile[ocol + i][orow];
    *(bf16x8*)(WT + (size_t)(c0 + orow) * D + r0 + ocol) = o;
  }
}

// ---------------------------------------------------------------------------
// build xa (bf16, MX x D): rows 0..4095 = x, 4096..4105 = adapter, rest 0
__global__ __launch_bounds__(256) void build_xa(const float* __restrict__ x,
                                                const float* __restrict__ ad,
                                                __bf16* __restrict__ xa) {
  int idx = blockIdx.x * 256 + threadIdx.x;
  int e = idx * 4;
  int row = e >> 12, col = e & 4095;
  f32x4 v = {};
  if (row < 4096)      v = *(const f32x4*)(x + (size_t)row * D + col);
  else if (row < 4106) v = *(const f32x4*)(ad + (size_t)(row - 4096) * D + col);
  bf16x4 o;
#pragma unroll
  for (int i = 0; i < 4; ++i) o[i] = (__bf16)v[i];
  *(bf16x4*)(xa + (size_t)row * D + col) = o;
}

// ---------------------------------------------------------------------------
// 8-phase GEMM, RACE-FIXED staging: 256x256 tile, BK=64, dbuf LDS (128KB).
// During K-tile k, the four phases each stage ONE half-tile of tile k+1 into
// slot (k+1)&1 (never the slot being read: each wave reads one A-half and
// one B-half of slot k&1 in ALL phases — R9's same-slot staging raced).
// vmcnt ledger (per wave, in-order): prologue 8 loads (tile 0); tile-k
// phase 0 issues +2 then vmcnt(2) drains exactly tile k's 8; vmcnt(0) at
// the last tile. 2 barriers/phase. 512 threads = 8 waves (2M x 4N).
// Swizzle: chunk cw of row R holds k-chunk cw^(R&7); staging pre-swizzles
// the global source, LDS dst linear (R7/R8-proven, 0 conflicts).
// MODE 0: fused QKV (bf16, routed by n-panel; rows 0..4095). MODE 1: f32.
template <int MODE>
__global__ __launch_bounds__(512, 2) void gemm256(const __bf16* __restrict__ A,
                                                  const __bf16* __restrict__ BT,
                                                  void* __restrict__ O0,
                                                  void* __restrict__ O1,
                                                  void* __restrict__ O2,
                                                  int Mt) {
  __shared__ __bf16 lds[65536];   // [2 slot][A|B][2 half][128][8 ch][8]
  const int tid = threadIdx.x;
  const int wv = tid >> 6, ln = tid & 63;
  const int lg = ln >> 4, lr = ln & 15;

  const int nwg = gridDim.x;
  const int wgid = xcd_chunk(blockIdx.x, nwg);
  const int m0 = (wgid % Mt) * 256;
  const int n0 = (wgid / Mt) * 256;
  const int wm = (wv >> 2) * 128, wn = (wv & 3) * 64;

  // stage one half-tile (mat 0=A/1=B, half 0/1) of K-tile k into slot k&1.
  // 2 gload_lds16 per thread = 16KB.
  auto stageHalf = [&](int k, int mat, int half) {
    const int slot = k & 1;
    const int kt = k * 64;
    const __bf16* base = mat ? BT + (size_t)(n0 + half * 128) * 4096
                             : A  + (size_t)(m0 + half * 128) * 4096;
#pragma unroll
    for (int i = 0; i < 2; ++i) {
      int c = i * 512 + tid;          // chunk 0..1023
      int r = c >> 3;                 // row-in-half 0..127
      int ch = (c & 7) ^ (r & 7);     // pre-swizzled source k-chunk
      gload_lds16(base + (size_t)r * 4096 + kt + ch * 8,
                  lds + slot * 32768 + mat * 16384 + half * 8192 +
                      (i * 512 + wv * 64) * 8);
    }
  };

  f32x4 acc[8][4] = {};
  bf16x8 aLo[4][2], aHi[4][2], bLo[2][2], bHi[2][2];

  // prologue: all 4 halves of tile 0 -> slot 0 (8 loads outstanding)
  stageHalf(0, 0, 0);
  stageHalf(0, 1, 0);
  stageHalf(0, 0, 1);
  stageHalf(0, 1, 1);

  for (int k = 0; k < 64; ++k) {
    const int slot = k & 1;
    const __bf16* pA = lds + slot * 32768;
    const __bf16* pB = lds + slot * 32768 + 16384;
    const bool pf = (k + 1 < 64);

    auto rdA = [&](int mi, int kk) -> bf16x8 {
      int r = wm + mi * 16 + lr;
      int R = r & 127;
      int cw = (kk * 4 + lg) ^ (R & 7);
      return *(const bf16x8*)(pA + (r >> 7) * 8192 + R * 64 + cw * 8);
    };
    auto rdB = [&](int ni, int kk) -> bf16x8 {
      int n = wn + ni * 16 + lr;
      int R = n & 127;
      int cw = (kk * 4 + lg) ^ (R & 7);
      return *(const bf16x8*)(pB + (n >> 7) * 8192 + R * 64 + cw * 8);
    };

    // ---- phase 0: stage A.lo(k+1) [other slot]; counted vmcnt; quad LoLo
    if (pf) stageHalf(k + 1, 0, 0);
    if (pf) asm volatile("s_waitcnt vmcnt(2)" ::: "memory");  // tile k landed
    else    asm volatile("s_waitcnt vmcnt(0)" ::: "memory");
    BARF();   // tile-k ready across all waves
#pragma unroll
    for (int mi = 0; mi < 4; ++mi)
#pragma unroll
      for (int kk = 0; kk < 2; ++kk) aLo[mi][kk] = rdA(mi, kk);
#pragma unroll
    for (int ni = 0; ni < 2; ++ni)
#pragma unroll
      for (int kk = 0; kk < 2; ++kk) bLo[ni][kk] = rdB(ni, kk);
    __builtin_amdgcn_s_setprio(1);
#pragma unroll
    for (int kk = 0; kk < 2; ++kk)
#pragma unroll
      for (int mi = 0; mi < 4; ++mi)
#pragma unroll
        for (int ni = 0; ni < 2; ++ni)
          acc[mi][ni] = mfma16(aLo[mi][kk], bLo[ni][kk], acc[mi][ni]);
    __builtin_amdgcn_s_setprio(0);
    BARF();

    // ---- phase 1: stage B.lo(k+1); quad HiLo (reuse bLo)
    if (pf) stageHalf(k + 1, 1, 0);
#pragma unroll
    for (int mi = 0; mi < 4; ++mi)
#pragma unroll
      for (int kk = 0; kk < 2; ++kk) aHi[mi][kk] = rdA(mi + 4, kk);
    BARF();
    __builtin_amdgcn_s_setprio(1);
#pragma unroll
    for (int kk = 0; kk < 2; ++kk)
#pragma unroll
      for (int mi = 0; mi < 4; ++mi)
#pragma unroll
        for (int ni = 0; ni < 2; ++ni)
          acc[mi + 4][ni] = mfma16(aHi[mi][kk], bLo[ni][kk], acc[mi + 4][ni]);
    __builtin_amdgcn_s_setprio(0);
    BARF();

    // ---- phase 2: stage A.hi(k+1); quad HiHi (reuse aHi)
    if (pf) stageHalf(k + 1, 0, 1);
#pragma unroll
    for (int ni = 0; ni < 2; ++ni)
#pragma unroll
      for (int kk = 0; kk < 2; ++kk) bHi[ni][kk] = rdB(ni + 2, kk);
    BARF();
    __builtin_amdgcn_s_setprio(1);
#pragma unroll
    for (int kk = 0; kk < 2; ++kk)
#pragma unroll
      for (int mi = 0; mi < 4; ++mi)
#pragma unroll
        for (int ni = 0; ni < 2; ++ni)
          acc[mi + 4][ni + 2] = mfma16(aHi[mi][kk], bHi[ni][kk], acc[mi + 4][ni + 2]);
    __builtin_amdgcn_s_setprio(0);
    BARF();

    // ---- phase 3: stage B.hi(k+1); quad LoHi (re-read aLo from slot k)
    if (pf) stageHalf(k + 1, 1, 1);
#pragma unroll
    for (int mi = 0; mi < 4; ++mi)
#pragma unroll
      for (int kk = 0; kk < 2; ++kk) aLo[mi][kk] = rdA(mi, kk);
    BARF();
    __builtin_amdgcn_s_setprio(1);
#pragma unroll
    for (int kk = 0; kk < 2; ++kk)
#pragma unroll
      for (int mi = 0; mi < 4; ++mi)
#pragma unroll
        for (int ni = 0; ni < 2; ++ni)
          acc[mi][ni + 2] = mfma16(aLo[mi][kk], bHi[ni][kk], acc[mi][ni + 2]);
    __builtin_amdgcn_s_setprio(0);
    BARF();
  }

  // epilogue
  if constexpr (MODE == 0) {
    const int sel = n0 >> 12;                 // 0=q, 1=k, 2=v
    __bf16* out = (sel == 0) ? (__bf16*)O0 : (sel == 1) ? (__bf16*)O1 : (__bf16*)O2;
    const int colb = n0 & 4095;
#pragma unroll
    for (int mi = 0; mi < 8; ++mi)
#pragma unroll
      for (int ni = 0; ni < 4; ++ni)
#pragma unroll
        for (int j = 0; j < 4; ++j) {
          int row = m0 + wm + mi * 16 + lg * 4 + j;
          int col = colb + wn + ni * 16 + lr;
          out[(size_t)row * 4096 + col] = (__bf16)acc[mi][ni][j];
        }
  } else {
    float* out = (float*)O0;
#pragma unroll
    for (int mi = 0; mi < 8; ++mi)
#pragma unroll
      for (int ni = 0; ni < 4; ++ni)
#pragma unroll
        for (int j = 0; j < 4; ++j) {
          int row = m0 + wm + mi * 16 + lg * 4 + j;
          int col = n0 + wn + ni * 16 + lr;
          out[(size_t)row * 4096 + col] = acc[mi][ni][j];
        }
  }
}

// ---------------------------------------------------------------------------
// Adapter mini-GEMM: rows 4096..4111 of kb|vb (= [adapter;pad] @ [wk|wv]).
// Direct-global fragments (tiny working set, L2/L3-resident). 32 blocks x
// 256 threads (4 waves x 64 cols). BT = wkT (fused k|v cols 0..8191).
__global__ __launch_bounds__(256) void gemm_adapter(const __bf16* __restrict__ xa,
                                                    const __bf16* __restrict__ BT,
                                                    __bf16* __restrict__ kb,
                                                    __bf16* __restrict__ vb) {
  const int tid = threadIdx.x;
  const int wv = tid >> 6, ln = tid & 63;
  const int lg = ln >> 4, lr = ln & 15;
  const int col0 = blockIdx.x * 256 + wv * 64;
  f32x4 acc[4] = {};
  for (int kt = 0; kt < 4096; kt += 32) {
    bf16x8 a = *(const bf16x8*)(xa + (size_t)(4096 + lr) * 4096 + kt + lg * 8);
#pragma unroll
    for (int ni = 0; ni < 4; ++ni) {
      bf16x8 b = *(const bf16x8*)(BT + (size_t)(col0 + ni * 16 + lr) * 4096 +
                                  kt + lg * 8);
      acc[ni] = mfma16(a, b, acc[ni]);
    }
  }
#pragma unroll
  for (int ni = 0; ni < 4; ++ni)
#pragma unroll
    for (int j = 0; j < 4; ++j) {
      int row = 4096 + lg * 4 + j;
      int col = col0 + ni * 16 + lr;
      __bf16* out = (col < 4096) ? kb : vb;
      out[(size_t)row * 4096 + (col & 4095)] = (__bf16)acc[ni][j];
    }
}

// ---------------------------------------------------------------------------
// RoPE in-place on q (4096 rows) and k (first 4096 rows).
__global__ __launch_bounds__(256) void rope_kernel(__bf16* __restrict__ q,
                                                   __bf16* __restrict__ k,
                                                   const float* __restrict__ fc,
                                                   const float* __restrict__ fs) {
  int row = blockIdx.x;
  __bf16* buf = blockIdx.y ? k : q;
  int t = threadIdx.x;
  int s = row & (SEQ - 1);
  int jb = (t & 7) * 8;
  const float* cp = fc + s * 64 + jb;
  const float* sp = fs + s * 64 + jb;
  __bf16* p = buf + (size_t)row * D + t * 16;
  bf16x8 v0 = *(const bf16x8*)p;
  bf16x8 v1 = *(const bf16x8*)(p + 8);
  bf16x8 o0, o1;
#pragma unroll
  for (int i = 0; i < 4; ++i) {
    float C = cp[i], Sn = sp[i];
    float re = (float)v0[2 * i], im = (float)v0[2 * i + 1];
    o0[2 * i]     = (__bf16)(re * C - im * Sn);
    o0[2 * i + 1] = (__bf16)(re * Sn + im * C);
  }
#pragma unroll
  for (int i = 0; i < 4; ++i) {
    float C = cp[4 + i], Sn = sp[4 + i];
    float re = (float)v1[2 * i], im = (float)v1[2 * i + 1];
    o1[2 * i]     = (__bf16)(re * C - im * Sn);
    o1[2 * i + 1] = (__bf16)(re * Sn + im * C);
  }
  *(bf16x8*)p = o0;
  *(bf16x8*)(p + 8) = o1;
}

// ---------------------------------------------------------------------------
// transpose V (MX x 4096 bf16) -> VT (4096 x MX bf16)
__global__ __launch_bounds__(256) void transpose_v(const __bf16* __restrict__ V,
                                                   __bf16* __restrict__ VT) {
  __shared__ __bf16 tile[64][72];
  const int t  = threadIdx.x;
  const int r0 = blockIdx.x * 64;
  const int c0 = blockIdx.y * 64;
#pragma unroll
  for (int p = 0; p < 2; ++p) {
    int e = p * 2048 + t * 8;
    int row = e >> 6, col = e & 63;
    bf16x8 v8 = *(const bf16x8*)(V + (size_t)(r0 + row) * D + c0 + col);
#pragma unroll
    for (int i = 0; i < 8; ++i) tile[row][col + i] = v8[i];
  }
  __syncthreads();
#pragma unroll
  for (int p = 0; p < 2; ++p) {
    int e = p * 2048 + t * 8;
    int orow = e >> 6, ocol = e & 63;
    bf16x8 o;
#pragma unroll
    for (int i = 0; i < 8; ++i) o[i] = tile[ocol + i][orow];
    *(bf16x8*)(VT + (size_t)(c0 + orow) * MX + r0 + ocol) = o;
  }
}

// ---------------------------------------------------------------------------
// Flash attention + adapter (unchanged from R6/R7/R8).
__global__ __launch_bounds__(256) void attn_kernel(const __bf16* __restrict__ Q,
                                                   const __bf16* __restrict__ K,
                                                   const __bf16* __restrict__ VT,
                                                   const float* __restrict__ gate,
                                                   __bf16* __restrict__ Out) {
  __shared__ __bf16 Ks[2][64 * 128];
  __shared__ __bf16 Vs[2][128 * 64];
  __shared__ __bf16 Ps[4][32 * 64];

  const int tid = threadIdx.x;
  const int wv = tid >> 6, ln = tid & 63;
  const int lg = ln >> 4, lr = ln & 15;

  const int wgid = xcd_chunk(blockIdx.x, 512);
  const int px = wgid & 7;
  const int hb = wgid >> 3;
  const int h = hb & 31, b = hb >> 5;

  const float scale = 0.08838834764831845f;
  const float g = tanhf(gate[h]);

  auto stage = [&](int t, int buf) {
    const int kv0 = t * 64;
#pragma unroll
    for (int j = 0; j < 4; ++j) {
      int c = wv * 256 + j * 64 + ln;
      int rk = c >> 4, sck = (c & 15) ^ (rk & 7);
      gload_lds16(K + (size_t)(b * SEQ + kv0 + rk) * D + h * 128 + sck * 8,
                  Ks[buf] + (wv * 256 + j * 64) * 8);
      int rv = c >> 3, scv = (c & 7) ^ (rv & 7);
      gload_lds16(VT + (size_t)(h * 128 + rv) * MX + b * SEQ + kv0 + scv * 8,
                  Vs[buf] + (wv * 256 + j * 64) * 8);
    }
  };

  auto run_supertile = [&](int qt) {
    const int q0 = qt * 128;
    const int qbase = b * SEQ + q0 + wv * 32;

    bf16x8 qf[2][4];
#pragma unroll
    for (int mi = 0; mi < 2; ++mi)
#pragma unroll
      for (int kd = 0; kd < 4; ++kd)
        qf[mi][kd] = *(const bf16x8*)(Q + (size_t)(qbase + mi * 16 + lr) * D +
                                      h * 128 + kd * 32 + lg * 8);

    f32x4 O[2][8] = {};
    float mI2[2], lI2[2];
#pragma unroll
    for (int mi = 0; mi < 2; ++mi) { mI2[mi] = -1e30f; lI2[mi] = 0.f; }

    const int ntiles = 2 * qt + 2;
    stage(0, 0);

    for (int t = 0; t < ntiles; ++t) {
      const int cur = t & 1;
      const int kv0 = t * 64;
      if (t + 1 < ntiles) {
        stage(t + 1, cur ^ 1);
        asm volatile("s_waitcnt vmcnt(8)" ::: "memory");
      } else {
        asm volatile("s_waitcnt vmcnt(0)" ::: "memory");
      }
      __builtin_amdgcn_s_barrier();
      __builtin_amdgcn_sched_barrier(0);

      f32x4 S[2][4] = {};
      __builtin_amdgcn_s_setprio(1);
#pragma unroll
      for (int kd = 0; kd < 4; ++kd) {
        bf16x8 kf[4];
#pragma unroll
        for (int nf = 0; nf < 4; ++nf) {
          int kr = nf * 16 + lr;
          kf[nf] = *(const bf16x8*)(Ks[cur] + kr * 128 +
                                    (((kd * 4 + lg) ^ (kr & 7)) * 8));
        }
#pragma unroll
        for (int mi = 0; mi < 2; ++mi)
#pragma unroll
          for (int nf = 0; nf < 4; ++nf)
            S[mi][nf] = mfma16(kf[nf], qf[mi][kd], S[mi][nf]);
      }
      __builtin_amdgcn_s_setprio(0);

      float r2[2]; int grew = 0;
#pragma unroll
      for (int mi = 0; mi < 2; ++mi) {
        const int qg = q0 + wv * 32 + mi * 16 + lr;
        float mo = mI2[mi];
        float mt = -3e38f;
#pragma unroll
        for (int nf = 0; nf < 4; ++nf)
#pragma unroll
          for (int j = 0; j < 4; ++j) {
            int kvg = kv0 + nf * 16 + lg * 4 + j;
            float s = S[mi][nf][j] * scale;
            s = (kvg > qg) ? -1e30f : s;
            S[mi][nf][j] = s;
            mt = fmaxf(mt, s);
          }
        mt = fmaxf(mt, __shfl_xor(mt, 16));
        mt = fmaxf(mt, __shfl_xor(mt, 32));
        float mn = fmaxf(mo, mt);
        float ps = 0.f;
#pragma unroll
        for (int nf = 0; nf < 4; ++nf)
#pragma unroll
          for (int j = 0; j < 4; ++j) {
            float p = __expf(S[mi][nf][j] - mn);
            S[mi][nf][j] = p;
            ps += p;
          }
        ps += __shfl_xor(ps, 16);
        ps += __shfl_xor(ps, 32);
        float r = __expf(mo - mn);
        lI2[mi] = lI2[mi] * r + ps;
        mI2[mi] = mn;
        r2[mi] = r;
        grew |= (mn > mo) ? 1 : 0;
      }
      if (__any(grew)) {
#pragma unroll
        for (int mi = 0; mi < 2; ++mi)
#pragma unroll
          for (int j = 0; j < 4; ++j) {
            float rj = __shfl(r2[mi], lg * 4 + j);
#pragma unroll
            for (int n = 0; n < 8; ++n) O[mi][n][j] *= rj;
          }
      }

#pragma unroll
      for (int mi = 0; mi < 2; ++mi) {
        int q = mi * 16 + lr;
#pragma unroll
        for (int nf = 0; nf < 4; ++nf)
#pragma unroll
          for (int jj = 0; jj < 2; ++jj) {
            int kv = nf * 16 + lg * 4 + 2 * jj;
            bf16x2 pk;
            pk[0] = (__bf16)S[mi][nf][2 * jj];
            pk[1] = (__bf16)S[mi][nf][2 * jj + 1];
            *(bf16x2*)(Ps[wv] + q * 64 + (((kv >> 3) ^ (q & 7)) * 8) + (kv & 7)) = pk;
          }
      }

      __builtin_amdgcn_s_setprio(1);
#pragma unroll
      for (int kkv = 0; kkv < 2; ++kkv) {
        bf16x8 pf[2];
#pragma unroll
        for (int mi = 0; mi < 2; ++mi) {
          int prw = mi * 16 + lr;
          pf[mi] = *(const bf16x8*)(Ps[wv] + prw * 64 +
                                    (((kkv * 4 + lg) ^ (prw & 7)) * 8));
        }
#pragma unroll
        for (int n = 0; n < 8; ++n) {
          int vr = n * 16 + lr;
          bf16x8 vf = *(const bf16x8*)(Vs[cur] + vr * 64 +
                                       (((kkv * 4 + lg) ^ (vr & 7)) * 8));
#pragma unroll
          for (int mi = 0; mi < 2; ++mi) O[mi][n] = mfma16(pf[mi], vf, O[mi][n]);
        }
      }
      __builtin_amdgcn_s_setprio(0);

      __builtin_amdgcn_s_barrier();
      __builtin_amdgcn_sched_barrier(0);
    }

#pragma unroll
    for (int mi = 0; mi < 2; ++mi) {
      float inv = 1.0f / lI2[mi];
#pragma unroll
      for (int j = 0; j < 4; ++j) {
        float invj = __shfl(inv, lg * 4 + j);
#pragma unroll
        for (int n = 0; n < 8; ++n) O[mi][n][j] *= invj;
      }
    }

    {
      f32x4 Sa[2] = {};
#pragma unroll
      for (int kd = 0; kd < 4; ++kd) {
        bf16x8 kfa = *(const bf16x8*)(K + (size_t)(2 * SEQ + lr) * D +
                                      h * 128 + kd * 32 + lg * 8);
#pragma unroll
        for (int mi = 0; mi < 2; ++mi) Sa[mi] = mfma16(kfa, qf[mi][kd], Sa[mi]);
      }
#pragma unroll
      for (int mi = 0; mi < 2; ++mi) {
        float mt = -3e38f;
#pragma unroll
        for (int j = 0; j < 4; ++j) {
          int kv = lg * 4 + j;
          float s = Sa[mi][j] * scale;
          s = (kv >= 10) ? -1e30f : s;
          Sa[mi][j] = s;
          mt = fmaxf(mt, s);
        }
        mt = fmaxf(mt, __shfl_xor(mt, 16));
        mt = fmaxf(mt, __shfl_xor(mt, 32));
        float ps = 0.f;
#pragma unroll
        for (int j = 0; j < 4; ++j) {
          float p = __expf(Sa[mi][j] - mt);
          Sa[mi][j] = p;
          ps += p;
        }
        ps += __shfl_xor(ps, 16);
        ps += __shfl_xor(ps, 32);
        float gs = g / ps;
        int q = mi * 16 + lr;
#pragma unroll
        for (int jj = 0; jj < 2; ++jj) {
          int kv = lg * 4 + 2 * jj;
          bf16x2 pk;
          pk[0] = (__bf16)(Sa[mi][2 * jj] * gs);
          pk[1] = (__bf16)(Sa[mi][2 * jj + 1] * gs);
          *(bf16x2*)(Ps[wv] + q * 64 + (((kv >> 3) ^ (q & 7)) * 8) + (kv & 7)) = pk;
          int kv2 = 16 + kv;
          bf16x2 z = {};
          *(bf16x2*)(Ps[wv] + q * 64 + (((kv2 >> 3) ^ (q & 7)) * 8) + (kv2 & 7)) = z;
        }
      }
      bf16x8 pfa[2];
#pragma unroll
      for (int mi = 0; mi < 2; ++mi) {
        int prw = mi * 16 + lr;
        pfa[mi] = *(const bf16x8*)(Ps[wv] + prw * 64 + ((lg ^ (prw & 7)) * 8));
      }
#pragma unroll
      for (int n = 0; n < 8; ++n) {
        bf16x8 vfa = *(const bf16x8*)(VT + (size_t)(h * 128 + n * 16 + lr) * MX +
                                      2 * SEQ + lg * 8);
#pragma unroll
        for (int mi = 0; mi < 2; ++mi) O[mi][n] = mfma16(pfa[mi], vfa, O[mi][n]);
      }
    }

#pragma unroll
    for (int mi = 0; mi < 2; ++mi)
#pragma unroll
      for (int n = 0; n < 8; ++n)
#pragma unroll
        for (int j = 0; j < 4; ++j)
          Out[(size_t)(qbase + mi * 16 + lg * 4 + j) * D + h * 128 + n * 16 + lr] =
              (__bf16)O[mi][n][j];
  };

  run_supertile(15 - px);
  run_supertile(px);
}

// ---------------------------------------------------------------------------
extern "C" void kernel_launch(void* const* d_in, const int* in_sizes, int n_in,
                              void* d_out, int out_size, void* d_ws, size_t ws_size,
                              hipStream_t stream) {
  const float* x    = (const float*)d_in[0];
  const float* wq   = (const float*)d_in[1];
  const float* wk   = (const float*)d_in[2];
  const float* wv   = (const float*)d_in[3];
  const float* wo   = (const float*)d_in[4];
  const float* gate = (const float*)d_in[5];
  const float* ad   = (const float*)d_in[6];
  const float* fc   = (const float*)d_in[7];
  const float* fs   = (const float*)d_in[8];

  const size_t WSZ = (size_t)D * D * 2;     // 33,554,432
  const size_t XSZ = (size_t)MX * D * 2;    // 34,603,008
  if (ws_size < 4 * WSZ + XSZ + WSZ + 3 * XSZ) return;  // 306,184,192 needed

  char* w = (char*)d_ws;
  size_t off = 0;
  auto alloc = [&](size_t sz) { void* p = w + off; off += sz; return p; };
  __bf16* wqT = (__bf16*)alloc(WSZ);   // wqT/wkT/wvT contiguous = fused 12288xK B^T
  __bf16* wkT = (__bf16*)alloc(WSZ);
  __bf16* wvT = (__bf16*)alloc(WSZ);
  __bf16* woT = (__bf16*)alloc(WSZ);
  __bf16* xa  = (__bf16*)alloc(XSZ);
  __bf16* qb  = (__bf16*)alloc(WSZ);
  __bf16* kb  = (__bf16*)alloc(XSZ);
  __bf16* vb  = (__bf16*)alloc(XSZ);
  __bf16* vT  = (__bf16*)alloc(XSZ);
  __bf16* attn = vb;   // vb dead after transpose_v; reuse as attention output

  dim3 blk(256);
  transpose_cast<<<dim3(64, 64), blk, 0, stream>>>(wq, wqT);
  transpose_cast<<<dim3(64, 64), blk, 0, stream>>>(wk, wkT);
  transpose_cast<<<dim3(64, 64), blk, 0, stream>>>(wv, wvT);
  transpose_cast<<<dim3(64, 64), blk, 0, stream>>>(wo, woT);
  build_xa<<<dim3(16896), blk, 0, stream>>>(x, ad, xa);

  // fused QKV GEMM: 16 M-tiles (rows 0..4095) x 48 N-tiles = 768 = 3x256.
  gemm256<0><<<dim3(16 * 48), dim3(512), 0, stream>>>(xa, wqT, qb, kb, vb, 16);
  // adapter rows 4096..4111 of kb|vb (10 real rows + zero pad).
  gemm_adapter<<<dim3(32), blk, 0, stream>>>(xa, wkT, kb, vb);

  rope_kernel<<<dim3(4096, 2), blk, 0, stream>>>(qb, kb, fc, fs);
  transpose_v<<<dim3(66, 64), blk, 0, stream>>>(vb, vT);

  attn_kernel<<<dim3(512), blk, 0, stream>>>(qb, kb, vT, gate, attn);

  gemm256<1><<<dim3(16 * 16), dim3(512), 0, stream>>>(attn, woT, d_out, nullptr, nullptr, 16);
}

// Round 11
// 897.599 us; speedup vs baseline: 1.3958x; 1.0004x over previous
//
#include <hip/hip_runtime.h>
#include <hip/hip_bf16.h>
#include <cstdint>

typedef float  f32x4  __attribute__((ext_vector_type(4)));
typedef __bf16 bf16x8 __attribute__((ext_vector_type(8)));
typedef __bf16 bf16x4 __attribute__((ext_vector_type(4)));
typedef __bf16 bf16x2 __attribute__((ext_vector_type(2)));

#define AS1 __attribute__((address_space(1)))
#define AS3 __attribute__((address_space(3)))

static constexpr int D   = 4096;
static constexpr int SEQ = 2048;
static constexpr int MX  = 4224;   // padded rows: 4096 x-rows + 10 adapter + pad

__device__ __forceinline__ void gload_lds16(const void* g, void* l) {
  __builtin_amdgcn_global_load_lds((AS1 void*)(g), (AS3 void*)(l), 16, 0, 0);
}

__device__ __forceinline__ f32x4 mfma16(bf16x8 a, bf16x8 b, f32x4 c) {
  return __builtin_amdgcn_mfma_f32_16x16x32_bf16(a, b, c, 0, 0, 0);
}

// bijective XCD-chunked remap (m204)
__device__ __forceinline__ int xcd_chunk(int orig, int nwg) {
  int q = nwg >> 3, r = nwg & 7;
  int xcd = orig & 7, pos = orig >> 3;
  return (xcd < r ? xcd * (q + 1) : r * (q + 1) + (xcd - r) * q) + pos;
}

// barrier that is also a compiler memory fence
#define BARF() asm volatile("s_barrier" ::: "memory")

// ---------------------------------------------------------------------------
// transpose + cast: W (f32, K x N row-major) -> WT (bf16, N x K row-major)
__global__ __launch_bounds__(256) void transpose_cast(const float* __restrict__ W,
                                                      __bf16* __restrict__ WT) {
  __shared__ float tile[64][65];
  const int t  = threadIdx.x;
  const int r0 = blockIdx.x * 64;
  const int c0 = blockIdx.y * 64;
#pragma unroll
  for (int p = 0; p < 4; ++p) {
    int e = p * 1024 + t * 4;
    int row = e >> 6, col = e & 63;
    f32x4 v = *(const f32x4*)(W + (size_t)(r0 + row) * D + c0 + col);
#pragma unroll
    for (int i = 0; i < 4; ++i) tile[row][col + i] = v[i];
  }
  __syncthreads();
#pragma unroll
  for (int p = 0; p < 2; ++p) {
    int e = p * 2048 + t * 8;
    int orow = e >> 6, ocol = e & 63;
    bf16x8 o;
#pragma unroll
    for (int i = 0; i < 8; ++i) o[i] = (__bf16)tile[ocol + i][orow];
    *(bf16x8*)(WT + (size_t)(c0 + orow) * D + r0 + ocol) = o;
  }
}

// ---------------------------------------------------------------------------
// build xa (bf16, MX x D): rows 0..4095 = x, 4096..4105 = adapter, rest 0
__global__ __launch_bounds__(256) void build_xa(const float* __restrict__ x,
                                                const float* __restrict__ ad,
                                                __bf16* __restrict__ xa) {
  int idx = blockIdx.x * 256 + threadIdx.x;
  int e = idx * 4;
  int row = e >> 12, col = e & 4095;
  f32x4 v = {};
  if (row < 4096)      v = *(const f32x4*)(x + (size_t)row * D + col);
  else if (row < 4106) v = *(const f32x4*)(ad + (size_t)(row - 4096) * D + col);
  bf16x4 o;
#pragma unroll
  for (int i = 0; i < 4; ++i) o[i] = (__bf16)v[i];
  *(bf16x4*)(xa + (size_t)row * D + col) = o;
}

// ---------------------------------------------------------------------------
// 8-phase GEMM (R10 structure, LDS-read-trimmed): 256x256 tile, BK=64, dbuf
// LDS (128KB). During K-tile k the four phases each stage ONE half-tile of
// tile k+1 into slot (k+1)&1 (never the slot being read). vmcnt ledger: tile-k
// phase 0 issues +2 then vmcnt(2) drains exactly tile k's 8; vmcnt(0) at the
// last tile. Unique fragment reads only (24 ds_read_b128/wave/tile; phase 3
// reuses aLo registers from phase 0 — they are never clobbered in between).
// 512 threads = 8 waves (2M x 4N). Swizzle: chunk cw of row R holds k-chunk
// cw^(R&7); staging pre-swizzles the global source, LDS dst linear.
// MODE 0: fused QKV (bf16, routed by n-panel; rows 0..4095). MODE 1: f32.
template <int MODE>
__global__ __launch_bounds__(512, 2) void gemm256(const __bf16* __restrict__ A,
                                                  const __bf16* __restrict__ BT,
                                                  void* __restrict__ O0,
                                                  void* __restrict__ O1,
                                                  void* __restrict__ O2,
                                                  int Mt) {
  __shared__ __bf16 lds[65536];   // [2 slot][A|B][2 half][128][8 ch][8]
  const int tid = threadIdx.x;
  const int wv = tid >> 6, ln = tid & 63;
  const int lg = ln >> 4, lr = ln & 15;

  const int nwg = gridDim.x;
  const int wgid = xcd_chunk(blockIdx.x, nwg);
  const int m0 = (wgid % Mt) * 256;
  const int n0 = (wgid / Mt) * 256;
  const int wm = (wv >> 2) * 128, wn = (wv & 3) * 64;

  // stage one half-tile (mat 0=A/1=B, half 0/1) of K-tile k into slot k&1.
  auto stageHalf = [&](int k, int mat, int half) {
    const int slot = k & 1;
    const int kt = k * 64;
    const __bf16* base = mat ? BT + (size_t)(n0 + half * 128) * 4096
                             : A  + (size_t)(m0 + half * 128) * 4096;
#pragma unroll
    for (int i = 0; i < 2; ++i) {
      int c = i * 512 + tid;          // chunk 0..1023
      int r = c >> 3;                 // row-in-half 0..127
      int ch = (c & 7) ^ (r & 7);     // pre-swizzled source k-chunk
      gload_lds16(base + (size_t)r * 4096 + kt + ch * 8,
                  lds + slot * 32768 + mat * 16384 + half * 8192 +
                      (i * 512 + wv * 64) * 8);
    }
  };

  f32x4 acc[8][4] = {};
  bf16x8 aLo[4][2], aHi[4][2], bLo[2][2], bHi[2][2];

  // prologue: all 4 halves of tile 0 -> slot 0 (8 loads outstanding)
  stageHalf(0, 0, 0);
  stageHalf(0, 1, 0);
  stageHalf(0, 0, 1);
  stageHalf(0, 1, 1);

  for (int k = 0; k < 64; ++k) {
    const int slot = k & 1;
    const __bf16* pA = lds + slot * 32768;
    const __bf16* pB = lds + slot * 32768 + 16384;
    const bool pf = (k + 1 < 64);

    auto rdA = [&](int mi, int kk) -> bf16x8 {
      int r = wm + mi * 16 + lr;
      int R = r & 127;
      int cw = (kk * 4 + lg) ^ (R & 7);
      return *(const bf16x8*)(pA + (r >> 7) * 8192 + R * 64 + cw * 8);
    };
    auto rdB = [&](int ni, int kk) -> bf16x8 {
      int n = wn + ni * 16 + lr;
      int R = n & 127;
      int cw = (kk * 4 + lg) ^ (R & 7);
      return *(const bf16x8*)(pB + (n >> 7) * 8192 + R * 64 + cw * 8);
    };

    // ---- phase 0: stage A.lo(k+1) [other slot]; counted vmcnt; quad LoLo
    if (pf) stageHalf(k + 1, 0, 0);
    if (pf) asm volatile("s_waitcnt vmcnt(2)" ::: "memory");  // tile k landed
    else    asm volatile("s_waitcnt vmcnt(0)" ::: "memory");
    BARF();   // tile-k ready across all waves
#pragma unroll
    for (int mi = 0; mi < 4; ++mi)
#pragma unroll
      for (int kk = 0; kk < 2; ++kk) aLo[mi][kk] = rdA(mi, kk);
#pragma unroll
    for (int ni = 0; ni < 2; ++ni)
#pragma unroll
      for (int kk = 0; kk < 2; ++kk) bLo[ni][kk] = rdB(ni, kk);
    __builtin_amdgcn_s_setprio(1);
#pragma unroll
    for (int kk = 0; kk < 2; ++kk)
#pragma unroll
      for (int mi = 0; mi < 4; ++mi)
#pragma unroll
        for (int ni = 0; ni < 2; ++ni)
          acc[mi][ni] = mfma16(aLo[mi][kk], bLo[ni][kk], acc[mi][ni]);
    __builtin_amdgcn_s_setprio(0);
    BARF();

    // ---- phase 1: stage B.lo(k+1); quad HiLo (reuse bLo)
    if (pf) stageHalf(k + 1, 1, 0);
#pragma unroll
    for (int mi = 0; mi < 4; ++mi)
#pragma unroll
      for (int kk = 0; kk < 2; ++kk) aHi[mi][kk] = rdA(mi + 4, kk);
    BARF();
    __builtin_amdgcn_s_setprio(1);
#pragma unroll
    for (int kk = 0; kk < 2; ++kk)
#pragma unroll
      for (int mi = 0; mi < 4; ++mi)
#pragma unroll
        for (int ni = 0; ni < 2; ++ni)
          acc[mi + 4][ni] = mfma16(aHi[mi][kk], bLo[ni][kk], acc[mi + 4][ni]);
    __builtin_amdgcn_s_setprio(0);
    BARF();

    // ---- phase 2: stage A.hi(k+1); quad HiHi (reuse aHi)
    if (pf) stageHalf(k + 1, 0, 1);
#pragma unroll
    for (int ni = 0; ni < 2; ++ni)
#pragma unroll
      for (int kk = 0; kk < 2; ++kk) bHi[ni][kk] = rdB(ni + 2, kk);
    BARF();
    __builtin_amdgcn_s_setprio(1);
#pragma unroll
    for (int kk = 0; kk < 2; ++kk)
#pragma unroll
      for (int mi = 0; mi < 4; ++mi)
#pragma unroll
        for (int ni = 0; ni < 2; ++ni)
          acc[mi + 4][ni + 2] = mfma16(aHi[mi][kk], bHi[ni][kk], acc[mi + 4][ni + 2]);
    __builtin_amdgcn_s_setprio(0);
    BARF();

    // ---- phase 3: stage B.hi(k+1); quad LoHi — aLo registers still valid
    // from phase 0 (phases 1/2 only write aHi/bHi): NO ds_reads here.
    if (pf) stageHalf(k + 1, 1, 1);
    BARF();
    __builtin_amdgcn_s_setprio(1);
#pragma unroll
    for (int kk = 0; kk < 2; ++kk)
#pragma unroll
      for (int mi = 0; mi < 4; ++mi)
#pragma unroll
        for (int ni = 0; ni < 2; ++ni)
          acc[mi][ni + 2] = mfma16(aLo[mi][kk], bHi[ni][kk], acc[mi][ni + 2]);
    __builtin_amdgcn_s_setprio(0);
    BARF();
  }

  // epilogue
  if constexpr (MODE == 0) {
    const int sel = n0 >> 12;                 // 0=q, 1=k, 2=v
    __bf16* out = (sel == 0) ? (__bf16*)O0 : (sel == 1) ? (__bf16*)O1 : (__bf16*)O2;
    const int colb = n0 & 4095;
#pragma unroll
    for (int mi = 0; mi < 8; ++mi)
#pragma unroll
      for (int ni = 0; ni < 4; ++ni)
#pragma unroll
        for (int j = 0; j < 4; ++j) {
          int row = m0 + wm + mi * 16 + lg * 4 + j;
          int col = colb + wn + ni * 16 + lr;
          out[(size_t)row * 4096 + col] = (__bf16)acc[mi][ni][j];
        }
  } else {
    float* out = (float*)O0;
#pragma unroll
    for (int mi = 0; mi < 8; ++mi)
#pragma unroll
      for (int ni = 0; ni < 4; ++ni)
#pragma unroll
        for (int j = 0; j < 4; ++j) {
          int row = m0 + wm + mi * 16 + lg * 4 + j;
          int col = n0 + wn + ni * 16 + lr;
          out[(size_t)row * 4096 + col] = acc[mi][ni][j];
        }
  }
}

// ---------------------------------------------------------------------------
// Adapter mini-GEMM: rows 4096..4111 of kb|vb (= [adapter;pad] @ [wk|wv]).
__global__ __launch_bounds__(256) void gemm_adapter(const __bf16* __restrict__ xa,
                                                    const __bf16* __restrict__ BT,
                                                    __bf16* __restrict__ kb,
                                                    __bf16* __restrict__ vb) {
  const int tid = threadIdx.x;
  const int wv = tid >> 6, ln = tid & 63;
  const int lg = ln >> 4, lr = ln & 15;
  const int col0 = blockIdx.x * 256 + wv * 64;
  f32x4 acc[4] = {};
  for (int kt = 0; kt < 4096; kt += 32) {
    bf16x8 a = *(const bf16x8*)(xa + (size_t)(4096 + lr) * 4096 + kt + lg * 8);
#pragma unroll
    for (int ni = 0; ni < 4; ++ni) {
      bf16x8 b = *(const bf16x8*)(BT + (size_t)(col0 + ni * 16 + lr) * 4096 +
                                  kt + lg * 8);
      acc[ni] = mfma16(a, b, acc[ni]);
    }
  }
#pragma unroll
  for (int ni = 0; ni < 4; ++ni)
#pragma unroll
    for (int j = 0; j < 4; ++j) {
      int row = 4096 + lg * 4 + j;
      int col = col0 + ni * 16 + lr;
      __bf16* out = (col < 4096) ? kb : vb;
      out[(size_t)row * 4096 + (col & 4095)] = (__bf16)acc[ni][j];
    }
}

// ---------------------------------------------------------------------------
// RoPE in-place on q (4096 rows) and k (first 4096 rows).
__global__ __launch_bounds__(256) void rope_kernel(__bf16* __restrict__ q,
                                                   __bf16* __restrict__ k,
                                                   const float* __restrict__ fc,
                                                   const float* __restrict__ fs) {
  int row = blockIdx.x;
  __bf16* buf = blockIdx.y ? k : q;
  int t = threadIdx.x;
  int s = row & (SEQ - 1);
  int jb = (t & 7) * 8;
  const float* cp = fc + s * 64 + jb;
  const float* sp = fs + s * 64 + jb;
  __bf16* p = buf + (size_t)row * D + t * 16;
  bf16x8 v0 = *(const bf16x8*)p;
  bf16x8 v1 = *(const bf16x8*)(p + 8);
  bf16x8 o0, o1;
#pragma unroll
  for (int i = 0; i < 4; ++i) {
    float C = cp[i], Sn = sp[i];
    float re = (float)v0[2 * i], im = (float)v0[2 * i + 1];
    o0[2 * i]     = (__bf16)(re * C - im * Sn);
    o0[2 * i + 1] = (__bf16)(re * Sn + im * C);
  }
#pragma unroll
  for (int i = 0; i < 4; ++i) {
    float C = cp[4 + i], Sn = sp[4 + i];
    float re = (float)v1[2 * i], im = (float)v1[2 * i + 1];
    o1[2 * i]     = (__bf16)(re * C - im * Sn);
    o1[2 * i + 1] = (__bf16)(re * Sn + im * C);
  }
  *(bf16x8*)p = o0;
  *(bf16x8*)(p + 8) = o1;
}

// ---------------------------------------------------------------------------
// transpose V (MX x 4096 bf16) -> VT (4096 x MX bf16)
__global__ __launch_bounds__(256) void transpose_v(const __bf16* __restrict__ V,
                                                   __bf16* __restrict__ VT) {
  __shared__ __bf16 tile[64][72];
  const int t  = threadIdx.x;
  const int r0 = blockIdx.x * 64;
  const int c0 = blockIdx.y * 64;
#pragma unroll
  for (int p = 0; p < 2; ++p) {
    int e = p * 2048 + t * 8;
    int row = e >> 6, col = e & 63;
    bf16x8 v8 = *(const bf16x8*)(V + (size_t)(r0 + row) * D + c0 + col);
#pragma unroll
    for (int i = 0; i < 8; ++i) tile[row][col + i] = v8[i];
  }
  __syncthreads();
#pragma unroll
  for (int p = 0; p < 2; ++p) {
    int e = p * 2048 + t * 8;
    int orow = e >> 6, ocol = e & 63;
    bf16x8 o;
#pragma unroll
    for (int i = 0; i < 8; ++i) o[i] = tile[ocol + i][orow];
    *(bf16x8*)(VT + (size_t)(c0 + orow) * MX + r0 + ocol) = o;
  }
}

// ---------------------------------------------------------------------------
// Flash attention + adapter (R10 structure; P-stores packed to bf16x4).
__global__ __launch_bounds__(256) void attn_kernel(const __bf16* __restrict__ Q,
                                                   const __bf16* __restrict__ K,
                                                   const __bf16* __restrict__ VT,
                                                   const float* __restrict__ gate,
                                                   __bf16* __restrict__ Out) {
  __shared__ __bf16 Ks[2][64 * 128];
  __shared__ __bf16 Vs[2][128 * 64];
  __shared__ __bf16 Ps[4][32 * 64];

  const int tid = threadIdx.x;
  const int wv = tid >> 6, ln = tid & 63;
  const int lg = ln >> 4, lr = ln & 15;

  const int wgid = xcd_chunk(blockIdx.x, 512);
  const int px = wgid & 7;
  const int hb = wgid >> 3;
  const int h = hb & 31, b = hb >> 5;

  const float scale = 0.08838834764831845f;
  const float g = tanhf(gate[h]);

  auto stage = [&](int t, int buf) {
    const int kv0 = t * 64;
#pragma unroll
    for (int j = 0; j < 4; ++j) {
      int c = wv * 256 + j * 64 + ln;
      int rk = c >> 4, sck = (c & 15) ^ (rk & 7);
      gload_lds16(K + (size_t)(b * SEQ + kv0 + rk) * D + h * 128 + sck * 8,
                  Ks[buf] + (wv * 256 + j * 64) * 8);
      int rv = c >> 3, scv = (c & 7) ^ (rv & 7);
      gload_lds16(VT + (size_t)(h * 128 + rv) * MX + b * SEQ + kv0 + scv * 8,
                  Vs[buf] + (wv * 256 + j * 64) * 8);
    }
  };

  auto run_supertile = [&](int qt) {
    const int q0 = qt * 128;
    const int qbase = b * SEQ + q0 + wv * 32;

    bf16x8 qf[2][4];
#pragma unroll
    for (int mi = 0; mi < 2; ++mi)
#pragma unroll
      for (int kd = 0; kd < 4; ++kd)
        qf[mi][kd] = *(const bf16x8*)(Q + (size_t)(qbase + mi * 16 + lr) * D +
                                      h * 128 + kd * 32 + lg * 8);

    f32x4 O[2][8] = {};
    float mI2[2], lI2[2];
#pragma unroll
    for (int mi = 0; mi < 2; ++mi) { mI2[mi] = -1e30f; lI2[mi] = 0.f; }

    const int ntiles = 2 * qt + 2;
    stage(0, 0);

    for (int t = 0; t < ntiles; ++t) {
      const int cur = t & 1;
      const int kv0 = t * 64;
      if (t + 1 < ntiles) {
        stage(t + 1, cur ^ 1);
        asm volatile("s_waitcnt vmcnt(8)" ::: "memory");
      } else {
        asm volatile("s_waitcnt vmcnt(0)" ::: "memory");
      }
      __builtin_amdgcn_s_barrier();
      __builtin_amdgcn_sched_barrier(0);

      f32x4 S[2][4] = {};
      __builtin_amdgcn_s_setprio(1);
#pragma unroll
      for (int kd = 0; kd < 4; ++kd) {
        bf16x8 kf[4];
#pragma unroll
        for (int nf = 0; nf < 4; ++nf) {
          int kr = nf * 16 + lr;
          kf[nf] = *(const bf16x8*)(Ks[cur] + kr * 128 +
                                    (((kd * 4 + lg) ^ (kr & 7)) * 8));
        }
#pragma unroll
        for (int mi = 0; mi < 2; ++mi)
#pragma unroll
          for (int nf = 0; nf < 4; ++nf)
            S[mi][nf] = mfma16(kf[nf], qf[mi][kd], S[mi][nf]);
      }
      __builtin_amdgcn_s_setprio(0);

      float r2[2]; int grew = 0;
#pragma unroll
      for (int mi = 0; mi < 2; ++mi) {
        const int qg = q0 + wv * 32 + mi * 16 + lr;
        float mo = mI2[mi];
        float mt = -3e38f;
#pragma unroll
        for (int nf = 0; nf < 4; ++nf)
#pragma unroll
          for (int j = 0; j < 4; ++j) {
            int kvg = kv0 + nf * 16 + lg * 4 + j;
            float s = S[mi][nf][j] * scale;
            s = (kvg > qg) ? -1e30f : s;
            S[mi][nf][j] = s;
            mt = fmaxf(mt, s);
          }
        mt = fmaxf(mt, __shfl_xor(mt, 16));
        mt = fmaxf(mt, __shfl_xor(mt, 32));
        float mn = fmaxf(mo, mt);
        float ps = 0.f;
#pragma unroll
        for (int nf = 0; nf < 4; ++nf)
#pragma unroll
          for (int j = 0; j < 4; ++j) {
            float p = __expf(S[mi][nf][j] - mn);
            S[mi][nf][j] = p;
            ps += p;
          }
        ps += __shfl_xor(ps, 16);
        ps += __shfl_xor(ps, 32);
        float r = __expf(mo - mn);
        lI2[mi] = lI2[mi] * r + ps;
        mI2[mi] = mn;
        r2[mi] = r;
        grew |= (mn > mo) ? 1 : 0;
      }
      if (__any(grew)) {
#pragma unroll
        for (int mi = 0; mi < 2; ++mi)
#pragma unroll
          for (int j = 0; j < 4; ++j) {
            float rj = __shfl(r2[mi], lg * 4 + j);
#pragma unroll
            for (int n = 0; n < 8; ++n) O[mi][n][j] *= rj;
          }
      }

      // P -> bf16x4 packed stores (kv = nf*16+lg*4..+3 contiguous in-chunk)
#pragma unroll
      for (int mi = 0; mi < 2; ++mi) {
        int q = mi * 16 + lr;
#pragma unroll
        for (int nf = 0; nf < 4; ++nf) {
          int kv = nf * 16 + lg * 4;
          bf16x4 pk;
#pragma unroll
          for (int j = 0; j < 4; ++j) pk[j] = (__bf16)S[mi][nf][j];
          *(bf16x4*)(Ps[wv] + q * 64 + (((kv >> 3) ^ (q & 7)) * 8) + (kv & 7)) = pk;
        }
      }

      __builtin_amdgcn_s_setprio(1);
#pragma unroll
      for (int kkv = 0; kkv < 2; ++kkv) {
        bf16x8 pf[2];
#pragma unroll
        for (int mi = 0; mi < 2; ++mi) {
          int prw = mi * 16 + lr;
          pf[mi] = *(const bf16x8*)(Ps[wv] + prw * 64 +
                                    (((kkv * 4 + lg) ^ (prw & 7)) * 8));
        }
#pragma unroll
        for (int n = 0; n < 8; ++n) {
          int vr = n * 16 + lr;
          bf16x8 vf = *(const bf16x8*)(Vs[cur] + vr * 64 +
                                       (((kkv * 4 + lg) ^ (vr & 7)) * 8));
#pragma unroll
          for (int mi = 0; mi < 2; ++mi) O[mi][n] = mfma16(pf[mi], vf, O[mi][n]);
        }
      }
      __builtin_amdgcn_s_setprio(0);

      __builtin_amdgcn_s_barrier();
      __builtin_amdgcn_sched_barrier(0);
    }

#pragma unroll
    for (int mi = 0; mi < 2; ++mi) {
      float inv = 1.0f / lI2[mi];
#pragma unroll
      for (int j = 0; j < 4; ++j) {
        float invj = __shfl(inv, lg * 4 + j);
#pragma unroll
        for (int n = 0; n < 8; ++n) O[mi][n][j] *= invj;
      }
    }

    {
      f32x4 Sa[2] = {};
#pragma unroll
      for (int kd = 0; kd < 4; ++kd) {
        bf16x8 kfa = *(const bf16x8*)(K + (size_t)(2 * SEQ + lr) * D +
                                      h * 128 + kd * 32 + lg * 8);
#pragma unroll
        for (int mi = 0; mi < 2; ++mi) Sa[mi] = mfma16(kfa, qf[mi][kd], Sa[mi]);
      }
#pragma unroll
      for (int mi = 0; mi < 2; ++mi) {
        float mt = -3e38f;
#pragma unroll
        for (int j = 0; j < 4; ++j) {
          int kv = lg * 4 + j;
          float s = Sa[mi][j] * scale;
          s = (kv >= 10) ? -1e30f : s;
          Sa[mi][j] = s;
          mt = fmaxf(mt, s);
        }
        mt = fmaxf(mt, __shfl_xor(mt, 16));
        mt = fmaxf(mt, __shfl_xor(mt, 32));
        float ps = 0.f;
#pragma unroll
        for (int j = 0; j < 4; ++j) {
          float p = __expf(Sa[mi][j] - mt);
          Sa[mi][j] = p;
          ps += p;
        }
        ps += __shfl_xor(ps, 16);
        ps += __shfl_xor(ps, 32);
        float gs = g / ps;
        int q = mi * 16 + lr;
        int kv = lg * 4;
        bf16x4 pk, z = {};
#pragma unroll
        for (int j = 0; j < 4; ++j) pk[j] = (__bf16)(Sa[mi][j] * gs);
        *(bf16x4*)(Ps[wv] + q * 64 + (((kv >> 3) ^ (q & 7)) * 8) + (kv & 7)) = pk;
        int kv2 = 16 + kv;
        *(bf16x4*)(Ps[wv] + q * 64 + (((kv2 >> 3) ^ (q & 7)) * 8) + (kv2 & 7)) = z;
      }
      bf16x8 pfa[2];
#pragma unroll
      for (int mi = 0; mi < 2; ++mi) {
        int prw = mi * 16 + lr;
        pfa[mi] = *(const bf16x8*)(Ps[wv] + prw * 64 + ((lg ^ (prw & 7)) * 8));
      }
#pragma unroll
      for (int n = 0; n < 8; ++n) {
        bf16x8 vfa = *(const bf16x8*)(VT + (size_t)(h * 128 + n * 16 + lr) * MX +
                                      2 * SEQ + lg * 8);
#pragma unroll
        for (int mi = 0; mi < 2; ++mi) O[mi][n] = mfma16(pfa[mi], vfa, O[mi][n]);
      }
    }

#pragma unroll
    for (int mi = 0; mi < 2; ++mi)
#pragma unroll
      for (int n = 0; n < 8; ++n)
#pragma unroll
        for (int j = 0; j < 4; ++j)
          Out[(size_t)(qbase + mi * 16 + lg * 4 + j) * D + h * 128 + n * 16 + lr] =
              (__bf16)O[mi][n][j];
  };

  run_supertile(15 - px);
  run_supertile(px);
}

// ---------------------------------------------------------------------------
extern "C" void kernel_launch(void* const* d_in, const int* in_sizes, int n_in,
                              void* d_out, int out_size, void* d_ws, size_t ws_size,
                              hipStream_t stream) {
  const float* x    = (const float*)d_in[0];
  const float* wq   = (const float*)d_in[1];
  const float* wk   = (const float*)d_in[2];
  const float* wv   = (const float*)d_in[3];
  const float* wo   = (const float*)d_in[4];
  const float* gate = (const float*)d_in[5];
  const float* ad   = (const float*)d_in[6];
  const float* fc   = (const float*)d_in[7];
  const float* fs   = (const float*)d_in[8];

  const size_t WSZ = (size_t)D * D * 2;     // 33,554,432
  const size_t XSZ = (size_t)MX * D * 2;    // 34,603,008
  if (ws_size < 4 * WSZ + XSZ + WSZ + 3 * XSZ) return;  // 306,184,192 needed

  char* w = (char*)d_ws;
  size_t off = 0;
  auto alloc = [&](size_t sz) { void* p = w + off; off += sz; return p; };
  __bf16* wqT = (__bf16*)alloc(WSZ);   // wqT/wkT/wvT contiguous = fused 12288xK B^T
  __bf16* wkT = (__bf16*)alloc(WSZ);
  __bf16* wvT = (__bf16*)alloc(WSZ);
  __bf16* woT = (__bf16*)alloc(WSZ);
  __bf16* xa  = (__bf16*)alloc(XSZ);
  __bf16* qb  = (__bf16*)alloc(WSZ);
  __bf16* kb  = (__bf16*)alloc(XSZ);
  __bf16* vb  = (__bf16*)alloc(XSZ);
  __bf16* vT  = (__bf16*)alloc(XSZ);
  __bf16* attn = vb;   // vb dead after transpose_v; reuse as attention output

  dim3 blk(256);
  transpose_cast<<<dim3(64, 64), blk, 0, stream>>>(wq, wqT);
  transpose_cast<<<dim3(64, 64), blk, 0, stream>>>(wk, wkT);
  transpose_cast<<<dim3(64, 64), blk, 0, stream>>>(wv, wvT);
  transpose_cast<<<dim3(64, 64), blk, 0, stream>>>(wo, woT);
  build_xa<<<dim3(16896), blk, 0, stream>>>(x, ad, xa);

  // fused QKV GEMM: 16 M-tiles (rows 0..4095) x 48 N-tiles = 768 = 3x256.
  gemm256<0><<<dim3(16 * 48), dim3(512), 0, stream>>>(xa, wqT, qb, kb, vb, 16);
  // adapter rows 4096..4111 of kb|vb (10 real rows + zero pad).
  gemm_adapter<<<dim3(32), blk, 0, stream>>>(xa, wkT, kb, vb);

  rope_kernel<<<dim3(4096, 2), blk, 0, stream>>>(qb, kb, fc, fs);
  transpose_v<<<dim3(66, 64), blk, 0, stream>>>(vb, vT);

  attn_kernel<<<dim3(512), blk, 0, stream>>>(qb, kb, vT, gate, attn);

  gemm256<1><<<dim3(16 * 16), dim3(512), 0, stream>>>(attn, woT, d_out, nullptr, nullptr, 16);
}

// Round 12
// 850.822 us; speedup vs baseline: 1.4726x; 1.0550x over previous
//
#include <hip/hip_runtime.h>
#include <hip/hip_bf16.h>
#include <cstdint>

typedef float  f32x4  __attribute__((ext_vector_type(4)));
typedef __bf16 bf16x8 __attribute__((ext_vector_type(8)));
typedef __bf16 bf16x4 __attribute__((ext_vector_type(4)));
typedef __bf16 bf16x2 __attribute__((ext_vector_type(2)));

#define AS1 __attribute__((address_space(1)))
#define AS3 __attribute__((address_space(3)))

static constexpr int D   = 4096;
static constexpr int SEQ = 2048;
static constexpr int MX  = 4224;   // padded rows: 4096 x-rows + 10 adapter + pad

__device__ __forceinline__ void gload_lds16(const void* g, void* l) {
  __builtin_amdgcn_global_load_lds((AS1 void*)(g), (AS3 void*)(l), 16, 0, 0);
}

__device__ __forceinline__ f32x4 mfma16(bf16x8 a, bf16x8 b, f32x4 c) {
  return __builtin_amdgcn_mfma_f32_16x16x32_bf16(a, b, c, 0, 0, 0);
}

// bijective XCD-chunked remap (m204)
__device__ __forceinline__ int xcd_chunk(int orig, int nwg) {
  int q = nwg >> 3, r = nwg & 7;
  int xcd = orig & 7, pos = orig >> 3;
  return (xcd < r ? xcd * (q + 1) : r * (q + 1) + (xcd - r) * q) + pos;
}

// barrier that is also a compiler memory fence
#define BARF() asm volatile("s_barrier" ::: "memory")

// ---------------------------------------------------------------------------
// transpose + cast: W (f32, K x N row-major) -> WT (bf16, N x K row-major)
__global__ __launch_bounds__(256) void transpose_cast(const float* __restrict__ W,
                                                      __bf16* __restrict__ WT) {
  __shared__ float tile[64][65];
  const int t  = threadIdx.x;
  const int r0 = blockIdx.x * 64;
  const int c0 = blockIdx.y * 64;
#pragma unroll
  for (int p = 0; p < 4; ++p) {
    int e = p * 1024 + t * 4;
    int row = e >> 6, col = e & 63;
    f32x4 v = *(const f32x4*)(W + (size_t)(r0 + row) * D + c0 + col);
#pragma unroll
    for (int i = 0; i < 4; ++i) tile[row][col + i] = v[i];
  }
  __syncthreads();
#pragma unroll
  for (int p = 0; p < 2; ++p) {
    int e = p * 2048 + t * 8;
    int orow = e >> 6, ocol = e & 63;
    bf16x8 o;
#pragma unroll
    for (int i = 0; i < 8; ++i) o[i] = (__bf16)tile[ocol + i][orow];
    *(bf16x8*)(WT + (size_t)(c0 + orow) * D + r0 + ocol) = o;
  }
}

// ---------------------------------------------------------------------------
// build xa (bf16, MX x D): rows 0..4095 = x, 4096..4105 = adapter, rest 0
__global__ __launch_bounds__(256) void build_xa(const float* __restrict__ x,
                                                const float* __restrict__ ad,
                                                __bf16* __restrict__ xa) {
  int idx = blockIdx.x * 256 + threadIdx.x;
  int e = idx * 4;
  int row = e >> 12, col = e & 4095;
  f32x4 v = {};
  if (row < 4096)      v = *(const f32x4*)(x + (size_t)row * D + col);
  else if (row < 4106) v = *(const f32x4*)(ad + (size_t)(row - 4096) * D + col);
  bf16x4 o;
#pragma unroll
  for (int i = 0; i < 4; ++i) o[i] = (__bf16)v[i];
  *(bf16x4*)(xa + (size_t)row * D + col) = o;
}

// ---------------------------------------------------------------------------
// 8-phase GEMM, never-drain pipeline (R12): 256x256 tile, BK=64, dbuf LDS.
// Stage plan: tile k stages {A.hi(k+1)@P0, B.hi(k+1)@P1, A.lo(k+2)@P2,
// B.lo(k+2)@P3}; prologue = 6 half-tiles. Waits: vmcnt(8) at P0 (confirms
// lo(k)+A.hi(k), issued 4-6 phases earlier) and P1 (confirms B.hi(k)); no
// waits at P2/P3 — >=8 loads stay in flight through tile 62; tile 63 peeled
// with vmcnt(0). P1/P2 fragment reads hoisted BEFORE their ready-barrier
// (data confirmed one phase earlier + barrier-propagated). Overwrite
// hazards: every staged half targets a region whose last reader finished
// >=2 barriers earlier (checked per half). 512 threads = 8 waves (2M x 4N).
// Swizzle: chunk cw of row R holds k-chunk cw^(R&7); staging pre-swizzles
// the global source, LDS dst linear (0 conflicts, R7-R11 proven).
// MODE 0: fused QKV (bf16, routed by n-panel; rows 0..4095). MODE 1: f32.
template <int MODE>
__global__ __launch_bounds__(512, 2) void gemm256(const __bf16* __restrict__ A,
                                                  const __bf16* __restrict__ BT,
                                                  void* __restrict__ O0,
                                                  void* __restrict__ O1,
                                                  void* __restrict__ O2,
                                                  int Mt) {
  __shared__ __bf16 lds[65536];   // [2 slot][A|B][2 half][128][8 ch][8]
  const int tid = threadIdx.x;
  const int wv = tid >> 6, ln = tid & 63;
  const int lg = ln >> 4, lr = ln & 15;

  const int nwg = gridDim.x;
  const int wgid = xcd_chunk(blockIdx.x, nwg);
  const int m0 = (wgid % Mt) * 256;
  const int n0 = (wgid / Mt) * 256;
  const int wm = (wv >> 2) * 128, wn = (wv & 3) * 64;

  // stage one half-tile (mat 0=A/1=B, half 0/1) of K-tile k into slot k&1.
  auto stageHalf = [&](int k, int mat, int half) {
    const int slot = k & 1;
    const int kt = k * 64;
    const __bf16* base = mat ? BT + (size_t)(n0 + half * 128) * 4096
                             : A  + (size_t)(m0 + half * 128) * 4096;
#pragma unroll
    for (int i = 0; i < 2; ++i) {
      int c = i * 512 + tid;          // chunk 0..1023
      int r = c >> 3;                 // row-in-half 0..127
      int ch = (c & 7) ^ (r & 7);     // pre-swizzled source k-chunk
      gload_lds16(base + (size_t)r * 4096 + kt + ch * 8,
                  lds + slot * 32768 + mat * 16384 + half * 8192 +
                      (i * 512 + wv * 64) * 8);
    }
  };

  f32x4 acc[8][4] = {};
  bf16x8 aLo[4][2], aHi[4][2], bLo[2][2], bHi[2][2];

  auto rdA = [&](const __bf16* pA, int mi, int kk) -> bf16x8 {
    int r = wm + mi * 16 + lr;
    int R = r & 127;
    int cw = (kk * 4 + lg) ^ (R & 7);
    return *(const bf16x8*)(pA + (r >> 7) * 8192 + R * 64 + cw * 8);
  };
  auto rdB = [&](const __bf16* pB, int ni, int kk) -> bf16x8 {
    int n = wn + ni * 16 + lr;
    int R = n & 127;
    int cw = (kk * 4 + lg) ^ (R & 7);
    return *(const bf16x8*)(pB + (n >> 7) * 8192 + R * 64 + cw * 8);
  };

  // prologue: 6 half-tiles (12 loads outstanding), issue order anchors ledger
  stageHalf(0, 0, 0);   // A.lo(0)
  stageHalf(0, 1, 0);   // B.lo(0)
  stageHalf(0, 0, 1);   // A.hi(0)
  stageHalf(0, 1, 1);   // B.hi(0)
  stageHalf(1, 0, 0);   // A.lo(1)
  stageHalf(1, 1, 0);   // B.lo(1)

  for (int k = 0; k < 63; ++k) {
    const int slot = k & 1;
    const __bf16* pA = lds + slot * 32768;
    const __bf16* pB = lds + slot * 32768 + 16384;

    // ---- P0: stage A.hi(k+1); vmcnt(8) confirms lo(k)+A.hi(k); quad LoLo
    stageHalf(k + 1, 0, 1);
    asm volatile("s_waitcnt vmcnt(8)" ::: "memory");
    BARF();
#pragma unroll
    for (int mi = 0; mi < 4; ++mi)
#pragma unroll
      for (int kk = 0; kk < 2; ++kk) aLo[mi][kk] = rdA(pA, mi, kk);
#pragma unroll
    for (int ni = 0; ni < 2; ++ni)
#pragma unroll
      for (int kk = 0; kk < 2; ++kk) bLo[ni][kk] = rdB(pB, ni, kk);
    __builtin_amdgcn_s_setprio(1);
#pragma unroll
    for (int kk = 0; kk < 2; ++kk)
#pragma unroll
      for (int mi = 0; mi < 4; ++mi)
#pragma unroll
        for (int ni = 0; ni < 2; ++ni)
          acc[mi][ni] = mfma16(aLo[mi][kk], bLo[ni][kk], acc[mi][ni]);
    __builtin_amdgcn_s_setprio(0);
    BARF();

    // ---- P1: stage B.hi(k+1); hoisted aHi reads; vmcnt(8) confirms B.hi(k)
    stageHalf(k + 1, 1, 1);
#pragma unroll
    for (int mi = 0; mi < 4; ++mi)
#pragma unroll
      for (int kk = 0; kk < 2; ++kk) aHi[mi][kk] = rdA(pA, mi + 4, kk);
    asm volatile("s_waitcnt vmcnt(8)" ::: "memory");
    BARF();
    __builtin_amdgcn_s_setprio(1);
#pragma unroll
    for (int kk = 0; kk < 2; ++kk)
#pragma unroll
      for (int mi = 0; mi < 4; ++mi)
#pragma unroll
        for (int ni = 0; ni < 2; ++ni)
          acc[mi + 4][ni] = mfma16(aHi[mi][kk], bLo[ni][kk], acc[mi + 4][ni]);
    __builtin_amdgcn_s_setprio(0);
    BARF();

    // ---- P2: stage A.lo(k+2); hoisted bHi reads; quad HiHi
    if (k + 2 < 64) stageHalf(k + 2, 0, 0);
#pragma unroll
    for (int ni = 0; ni < 2; ++ni)
#pragma unroll
      for (int kk = 0; kk < 2; ++kk) bHi[ni][kk] = rdB(pB, ni + 2, kk);
    BARF();
    __builtin_amdgcn_s_setprio(1);
#pragma unroll
    for (int kk = 0; kk < 2; ++kk)
#pragma unroll
      for (int mi = 0; mi < 4; ++mi)
#pragma unroll
        for (int ni = 0; ni < 2; ++ni)
          acc[mi + 4][ni + 2] = mfma16(aHi[mi][kk], bHi[ni][kk], acc[mi + 4][ni + 2]);
    __builtin_amdgcn_s_setprio(0);
    BARF();

    // ---- P3: stage B.lo(k+2); quad LoHi (aLo registers still valid)
    if (k + 2 < 64) stageHalf(k + 2, 1, 0);
    BARF();
    __builtin_amdgcn_s_setprio(1);
#pragma unroll
    for (int kk = 0; kk < 2; ++kk)
#pragma unroll
      for (int mi = 0; mi < 4; ++mi)
#pragma unroll
        for (int ni = 0; ni < 2; ++ni)
          acc[mi][ni + 2] = mfma16(aLo[mi][kk], bHi[ni][kk], acc[mi][ni + 2]);
    __builtin_amdgcn_s_setprio(0);
    BARF();
  }

  // ---- tile 63 peeled: drain everything once, no staging
  {
    const __bf16* pA = lds + (63 & 1) * 32768;
    const __bf16* pB = lds + (63 & 1) * 32768 + 16384;
    asm volatile("s_waitcnt vmcnt(0)" ::: "memory");
    BARF();
#pragma unroll
    for (int mi = 0; mi < 4; ++mi)
#pragma unroll
      for (int kk = 0; kk < 2; ++kk) aLo[mi][kk] = rdA(pA, mi, kk);
#pragma unroll
    for (int ni = 0; ni < 2; ++ni)
#pragma unroll
      for (int kk = 0; kk < 2; ++kk) bLo[ni][kk] = rdB(pB, ni, kk);
#pragma unroll
    for (int kk = 0; kk < 2; ++kk)
#pragma unroll
      for (int mi = 0; mi < 4; ++mi)
#pragma unroll
        for (int ni = 0; ni < 2; ++ni)
          acc[mi][ni] = mfma16(aLo[mi][kk], bLo[ni][kk], acc[mi][ni]);
#pragma unroll
    for (int mi = 0; mi < 4; ++mi)
#pragma unroll
      for (int kk = 0; kk < 2; ++kk) aHi[mi][kk] = rdA(pA, mi + 4, kk);
#pragma unroll
    for (int ni = 0; ni < 2; ++ni)
#pragma unroll
      for (int kk = 0; kk < 2; ++kk) bHi[ni][kk] = rdB(pB, ni + 2, kk);
#pragma unroll
    for (int kk = 0; kk < 2; ++kk)
#pragma unroll
      for (int mi = 0; mi < 4; ++mi)
#pragma unroll
        for (int ni = 0; ni < 2; ++ni) {
          acc[mi + 4][ni]     = mfma16(aHi[mi][kk], bLo[ni][kk], acc[mi + 4][ni]);
          acc[mi + 4][ni + 2] = mfma16(aHi[mi][kk], bHi[ni][kk], acc[mi + 4][ni + 2]);
          acc[mi][ni + 2]     = mfma16(aLo[mi][kk], bHi[ni][kk], acc[mi][ni + 2]);
        }
  }

  // epilogue
  if constexpr (MODE == 0) {
    const int sel = n0 >> 12;                 // 0=q, 1=k, 2=v
    __bf16* out = (sel == 0) ? (__bf16*)O0 : (sel == 1) ? (__bf16*)O1 : (__bf16*)O2;
    const int colb = n0 & 4095;
#pragma unroll
    for (int mi = 0; mi < 8; ++mi)
#pragma unroll
      for (int ni = 0; ni < 4; ++ni)
#pragma unroll
        for (int j = 0; j < 4; ++j) {
          int row = m0 + wm + mi * 16 + lg * 4 + j;
          int col = colb + wn + ni * 16 + lr;
          out[(size_t)row * 4096 + col] = (__bf16)acc[mi][ni][j];
        }
  } else {
    float* out = (float*)O0;
#pragma unroll
    for (int mi = 0; mi < 8; ++mi)
#pragma unroll
      for (int ni = 0; ni < 4; ++ni)
#pragma unroll
        for (int j = 0; j < 4; ++j) {
          int row = m0 + wm + mi * 16 + lg * 4 + j;
          int col = n0 + wn + ni * 16 + lr;
          out[(size_t)row * 4096 + col] = acc[mi][ni][j];
        }
  }
}

// ---------------------------------------------------------------------------
// Adapter mini-GEMM: rows 4096..4111 of kb|vb (= [adapter;pad] @ [wk|wv]).
__global__ __launch_bounds__(256) void gemm_adapter(const __bf16* __restrict__ xa,
                                                    const __bf16* __restrict__ BT,
                                                    __bf16* __restrict__ kb,
                                                    __bf16* __restrict__ vb) {
  const int tid = threadIdx.x;
  const int wv = tid >> 6, ln = tid & 63;
  const int lg = ln >> 4, lr = ln & 15;
  const int col0 = blockIdx.x * 256 + wv * 64;
  f32x4 acc[4] = {};
  for (int kt = 0; kt < 4096; kt += 32) {
    bf16x8 a = *(const bf16x8*)(xa + (size_t)(4096 + lr) * 4096 + kt + lg * 8);
#pragma unroll
    for (int ni = 0; ni < 4; ++ni) {
      bf16x8 b = *(const bf16x8*)(BT + (size_t)(col0 + ni * 16 + lr) * 4096 +
                                  kt + lg * 8);
      acc[ni] = mfma16(a, b, acc[ni]);
    }
  }
#pragma unroll
  for (int ni = 0; ni < 4; ++ni)
#pragma unroll
    for (int j = 0; j < 4; ++j) {
      int row = 4096 + lg * 4 + j;
      int col = col0 + ni * 16 + lr;
      __bf16* out = (col < 4096) ? kb : vb;
      out[(size_t)row * 4096 + (col & 4095)] = (__bf16)acc[ni][j];
    }
}

// ---------------------------------------------------------------------------
// RoPE in-place on q (4096 rows) and k (first 4096 rows).
__global__ __launch_bounds__(256) void rope_kernel(__bf16* __restrict__ q,
                                                   __bf16* __restrict__ k,
                                                   const float* __restrict__ fc,
                                                   const float* __restrict__ fs) {
  int row = blockIdx.x;
  __bf16* buf = blockIdx.y ? k : q;
  int t = threadIdx.x;
  int s = row & (SEQ - 1);
  int jb = (t & 7) * 8;
  const float* cp = fc + s * 64 + jb;
  const float* sp = fs + s * 64 + jb;
  __bf16* p = buf + (size_t)row * D + t * 16;
  bf16x8 v0 = *(const bf16x8*)p;
  bf16x8 v1 = *(const bf16x8*)(p + 8);
  bf16x8 o0, o1;
#pragma unroll
  for (int i = 0; i < 4; ++i) {
    float C = cp[i], Sn = sp[i];
    float re = (float)v0[2 * i], im = (float)v0[2 * i + 1];
    o0[2 * i]     = (__bf16)(re * C - im * Sn);
    o0[2 * i + 1] = (__bf16)(re * Sn + im * C);
  }
#pragma unroll
  for (int i = 0; i < 4; ++i) {
    float C = cp[4 + i], Sn = sp[4 + i];
    float re = (float)v1[2 * i], im = (float)v1[2 * i + 1];
    o1[2 * i]     = (__bf16)(re * C - im * Sn);
    o1[2 * i + 1] = (__bf16)(re * Sn + im * C);
  }
  *(bf16x8*)p = o0;
  *(bf16x8*)(p + 8) = o1;
}

// ---------------------------------------------------------------------------
// transpose V (MX x 4096 bf16) -> VT (4096 x MX bf16)
__global__ __launch_bounds__(256) void transpose_v(const __bf16* __restrict__ V,
                                                   __bf16* __restrict__ VT) {
  __shared__ __bf16 tile[64][72];
  const int t  = threadIdx.x;
  const int r0 = blockIdx.x * 64;
  const int c0 = blockIdx.y * 64;
#pragma unroll
  for (int p = 0; p < 2; ++p) {
    int e = p * 2048 + t * 8;
    int row = e >> 6, col = e & 63;
    bf16x8 v8 = *(const bf16x8*)(V + (size_t)(r0 + row) * D + c0 + col);
#pragma unroll
    for (int i = 0; i < 8; ++i) tile[row][col + i] = v8[i];
  }
  __syncthreads();
#pragma unroll
  for (int p = 0; p < 2; ++p) {
    int e = p * 2048 + t * 8;
    int orow = e >> 6, ocol = e & 63;
    bf16x8 o;
#pragma unroll
    for (int i = 0; i < 8; ++i) o[i] = tile[ocol + i][orow];
    *(bf16x8*)(VT + (size_t)(c0 + orow) * MX + r0 + ocol) = o;
  }
}

// ---------------------------------------------------------------------------
// Flash attention + adapter (unchanged from R11, which passed).
__global__ __launch_bounds__(256) void attn_kernel(const __bf16* __restrict__ Q,
                                                   const __bf16* __restrict__ K,
                                                   const __bf16* __restrict__ VT,
                                                   const float* __restrict__ gate,
                                                   __bf16* __restrict__ Out) {
  __shared__ __bf16 Ks[2][64 * 128];
  __shared__ __bf16 Vs[2][128 * 64];
  __shared__ __bf16 Ps[4][32 * 64];

  const int tid = threadIdx.x;
  const int wv = tid >> 6, ln = tid & 63;
  const int lg = ln >> 4, lr = ln & 15;

  const int wgid = xcd_chunk(blockIdx.x, 512);
  const int px = wgid & 7;
  const int hb = wgid >> 3;
  const int h = hb & 31, b = hb >> 5;

  const float scale = 0.08838834764831845f;
  const float g = tanhf(gate[h]);

  auto stage = [&](int t, int buf) {
    const int kv0 = t * 64;
#pragma unroll
    for (int j = 0; j < 4; ++j) {
      int c = wv * 256 + j * 64 + ln;
      int rk = c >> 4, sck = (c & 15) ^ (rk & 7);
      gload_lds16(K + (size_t)(b * SEQ + kv0 + rk) * D + h * 128 + sck * 8,
                  Ks[buf] + (wv * 256 + j * 64) * 8);
      int rv = c >> 3, scv = (c & 7) ^ (rv & 7);
      gload_lds16(VT + (size_t)(h * 128 + rv) * MX + b * SEQ + kv0 + scv * 8,
                  Vs[buf] + (wv * 256 + j * 64) * 8);
    }
  };

  auto run_supertile = [&](int qt) {
    const int q0 = qt * 128;
    const int qbase = b * SEQ + q0 + wv * 32;

    bf16x8 qf[2][4];
#pragma unroll
    for (int mi = 0; mi < 2; ++mi)
#pragma unroll
      for (int kd = 0; kd < 4; ++kd)
        qf[mi][kd] = *(const bf16x8*)(Q + (size_t)(qbase + mi * 16 + lr) * D +
                                      h * 128 + kd * 32 + lg * 8);

    f32x4 O[2][8] = {};
    float mI2[2], lI2[2];
#pragma unroll
    for (int mi = 0; mi < 2; ++mi) { mI2[mi] = -1e30f; lI2[mi] = 0.f; }

    const int ntiles = 2 * qt + 2;
    stage(0, 0);

    for (int t = 0; t < ntiles; ++t) {
      const int cur = t & 1;
      const int kv0 = t * 64;
      if (t + 1 < ntiles) {
        stage(t + 1, cur ^ 1);
        asm volatile("s_waitcnt vmcnt(8)" ::: "memory");
      } else {
        asm volatile("s_waitcnt vmcnt(0)" ::: "memory");
      }
      __builtin_amdgcn_s_barrier();
      __builtin_amdgcn_sched_barrier(0);

      f32x4 S[2][4] = {};
      __builtin_amdgcn_s_setprio(1);
#pragma unroll
      for (int kd = 0; kd < 4; ++kd) {
        bf16x8 kf[4];
#pragma unroll
        for (int nf = 0; nf < 4; ++nf) {
          int kr = nf * 16 + lr;
          kf[nf] = *(const bf16x8*)(Ks[cur] + kr * 128 +
                                    (((kd * 4 + lg) ^ (kr & 7)) * 8));
        }
#pragma unroll
        for (int mi = 0; mi < 2; ++mi)
#pragma unroll
          for (int nf = 0; nf < 4; ++nf)
            S[mi][nf] = mfma16(kf[nf], qf[mi][kd], S[mi][nf]);
      }
      __builtin_amdgcn_s_setprio(0);

      float r2[2]; int grew = 0;
#pragma unroll
      for (int mi = 0; mi < 2; ++mi) {
        const int qg = q0 + wv * 32 + mi * 16 + lr;
        float mo = mI2[mi];
        float mt = -3e38f;
#pragma unroll
        for (int nf = 0; nf < 4; ++nf)
#pragma unroll
          for (int j = 0; j < 4; ++j) {
            int kvg = kv0 + nf * 16 + lg * 4 + j;
            float s = S[mi][nf][j] * scale;
            s = (kvg > qg) ? -1e30f : s;
            S[mi][nf][j] = s;
            mt = fmaxf(mt, s);
          }
        mt = fmaxf(mt, __shfl_xor(mt, 16));
        mt = fmaxf(mt, __shfl_xor(mt, 32));
        float mn = fmaxf(mo, mt);
        float ps = 0.f;
#pragma unroll
        for (int nf = 0; nf < 4; ++nf)
#pragma unroll
          for (int j = 0; j < 4; ++j) {
            float p = __expf(S[mi][nf][j] - mn);
            S[mi][nf][j] = p;
            ps += p;
          }
        ps += __shfl_xor(ps, 16);
        ps += __shfl_xor(ps, 32);
        float r = __expf(mo - mn);
        lI2[mi] = lI2[mi] * r + ps;
        mI2[mi] = mn;
        r2[mi] = r;
        grew |= (mn > mo) ? 1 : 0;
      }
      if (__any(grew)) {
#pragma unroll
        for (int mi = 0; mi < 2; ++mi)
#pragma unroll
          for (int j = 0; j < 4; ++j) {
            float rj = __shfl(r2[mi], lg * 4 + j);
#pragma unroll
            for (int n = 0; n < 8; ++n) O[mi][n][j] *= rj;
          }
      }

      // P -> bf16x4 packed stores (kv = nf*16+lg*4..+3 contiguous in-chunk)
#pragma unroll
      for (int mi = 0; mi < 2; ++mi) {
        int q = mi * 16 + lr;
#pragma unroll
        for (int nf = 0; nf < 4; ++nf) {
          int kv = nf * 16 + lg * 4;
          bf16x4 pk;
#pragma unroll
          for (int j = 0; j < 4; ++j) pk[j] = (__bf16)S[mi][nf][j];
          *(bf16x4*)(Ps[wv] + q * 64 + (((kv >> 3) ^ (q & 7)) * 8) + (kv & 7)) = pk;
        }
      }

      __builtin_amdgcn_s_setprio(1);
#pragma unroll
      for (int kkv = 0; kkv < 2; ++kkv) {
        bf16x8 pf[2];
#pragma unroll
        for (int mi = 0; mi < 2; ++mi) {
          int prw = mi * 16 + lr;
          pf[mi] = *(const bf16x8*)(Ps[wv] + prw * 64 +
                                    (((kkv * 4 + lg) ^ (prw & 7)) * 8));
        }
#pragma unroll
        for (int n = 0; n < 8; ++n) {
          int vr = n * 16 + lr;
          bf16x8 vf = *(const bf16x8*)(Vs[cur] + vr * 64 +
                                       (((kkv * 4 + lg) ^ (vr & 7)) * 8));
#pragma unroll
          for (int mi = 0; mi < 2; ++mi) O[mi][n] = mfma16(pf[mi], vf, O[mi][n]);
        }
      }
      __builtin_amdgcn_s_setprio(0);

      __builtin_amdgcn_s_barrier();
      __builtin_amdgcn_sched_barrier(0);
    }

#pragma unroll
    for (int mi = 0; mi < 2; ++mi) {
      float inv = 1.0f / lI2[mi];
#pragma unroll
      for (int j = 0; j < 4; ++j) {
        float invj = __shfl(inv, lg * 4 + j);
#pragma unroll
        for (int n = 0; n < 8; ++n) O[mi][n][j] *= invj;
      }
    }

    {
      f32x4 Sa[2] = {};
#pragma unroll
      for (int kd = 0; kd < 4; ++kd) {
        bf16x8 kfa = *(const bf16x8*)(K + (size_t)(2 * SEQ + lr) * D +
                                      h * 128 + kd * 32 + lg * 8);
#pragma unroll
        for (int mi = 0; mi < 2; ++mi) Sa[mi] = mfma16(kfa, qf[mi][kd], Sa[mi]);
      }
#pragma unroll
      for (int mi = 0; mi < 2; ++mi) {
        float mt = -3e38f;
#pragma unroll
        for (int j = 0; j < 4; ++j) {
          int kv = lg * 4 + j;
          float s = Sa[mi][j] * scale;
          s = (kv >= 10) ? -1e30f : s;
          Sa[mi][j] = s;
          mt = fmaxf(mt, s);
        }
        mt = fmaxf(mt, __shfl_xor(mt, 16));
        mt = fmaxf(mt, __shfl_xor(mt, 32));
        float ps = 0.f;
#pragma unroll
        for (int j = 0; j < 4; ++j) {
          float p = __expf(Sa[mi][j] - mt);
          Sa[mi][j] = p;
          ps += p;
        }
        ps += __shfl_xor(ps, 16);
        ps += __shfl_xor(ps, 32);
        float gs = g / ps;
        int q = mi * 16 + lr;
        int kv = lg * 4;
        bf16x4 pk, z = {};
#pragma unroll
        for (int j = 0; j < 4; ++j) pk[j] = (__bf16)(Sa[mi][j] * gs);
        *(bf16x4*)(Ps[wv] + q * 64 + (((kv >> 3) ^ (q & 7)) * 8) + (kv & 7)) = pk;
        int kv2 = 16 + kv;
        *(bf16x4*)(Ps[wv] + q * 64 + (((kv2 >> 3) ^ (q & 7)) * 8) + (kv2 & 7)) = z;
      }
      bf16x8 pfa[2];
#pragma unroll
      for (int mi = 0; mi < 2; ++mi) {
        int prw = mi * 16 + lr;
        pfa[mi] = *(const bf16x8*)(Ps[wv] + prw * 64 + ((lg ^ (prw & 7)) * 8));
      }
#pragma unroll
      for (int n = 0; n < 8; ++n) {
        bf16x8 vfa = *(const bf16x8*)(VT + (size_t)(h * 128 + n * 16 + lr) * MX +
                                      2 * SEQ + lg * 8);
#pragma unroll
        for (int mi = 0; mi < 2; ++mi) O[mi][n] = mfma16(pfa[mi], vfa, O[mi][n]);
      }
    }

#pragma unroll
    for (int mi = 0; mi < 2; ++mi)
#pragma unroll
      for (int n = 0; n < 8; ++n)
#pragma unroll
        for (int j = 0; j < 4; ++j)
          Out[(size_t)(qbase + mi * 16 + lg * 4 + j) * D + h * 128 + n * 16 + lr] =
              (__bf16)O[mi][n][j];
  };

  run_supertile(15 - px);
  run_supertile(px);
}

// ---------------------------------------------------------------------------
extern "C" void kernel_launch(void* const* d_in, const int* in_sizes, int n_in,
                              void* d_out, int out_size, void* d_ws, size_t ws_size,
                              hipStream_t stream) {
  const float* x    = (const float*)d_in[0];
  const float* wq   = (const float*)d_in[1];
  const float* wk   = (const float*)d_in[2];
  const float* wv   = (const float*)d_in[3];
  const float* wo   = (const float*)d_in[4];
  const float* gate = (const float*)d_in[5];
  const float* ad   = (const float*)d_in[6];
  const float* fc   = (const float*)d_in[7];
  const float* fs   = (const float*)d_in[8];

  const size_t WSZ = (size_t)D * D * 2;     // 33,554,432
  const size_t XSZ = (size_t)MX * D * 2;    // 34,603,008
  if (ws_size < 4 * WSZ + XSZ + WSZ + 3 * XSZ) return;  // 306,184,192 needed

  char* w = (char*)d_ws;
  size_t off = 0;
  auto alloc = [&](size_t sz) { void* p = w + off; off += sz; return p; };
  __bf16* wqT = (__bf16*)alloc(WSZ);   // wqT/wkT/wvT contiguous = fused 12288xK B^T
  __bf16* wkT = (__bf16*)alloc(WSZ);
  __bf16* wvT = (__bf16*)alloc(WSZ);
  __bf16* woT = (__bf16*)alloc(WSZ);
  __bf16* xa  = (__bf16*)alloc(XSZ);
  __bf16* qb  = (__bf16*)alloc(WSZ);
  __bf16* kb  = (__bf16*)alloc(XSZ);
  __bf16* vb  = (__bf16*)alloc(XSZ);
  __bf16* vT  = (__bf16*)alloc(XSZ);
  __bf16* attn = vb;   // vb dead after transpose_v; reuse as attention output

  dim3 blk(256);
  transpose_cast<<<dim3(64, 64), blk, 0, stream>>>(wq, wqT);
  transpose_cast<<<dim3(64, 64), blk, 0, stream>>>(wk, wkT);
  transpose_cast<<<dim3(64, 64), blk, 0, stream>>>(wv, wvT);
  transpose_cast<<<dim3(64, 64), blk, 0, stream>>>(wo, woT);
  build_xa<<<dim3(16896), blk, 0, stream>>>(x, ad, xa);

  // fused QKV GEMM: 16 M-tiles (rows 0..4095) x 48 N-tiles = 768 = 3x256.
  gemm256<0><<<dim3(16 * 48), dim3(512), 0, stream>>>(xa, wqT, qb, kb, vb, 16);
  // adapter rows 4096..4111 of kb|vb (10 real rows + zero pad).
  gemm_adapter<<<dim3(32), blk, 0, stream>>>(xa, wkT, kb, vb);

  rope_kernel<<<dim3(4096, 2), blk, 0, stream>>>(qb, kb, fc, fs);
  transpose_v<<<dim3(66, 64), blk, 0, stream>>>(vb, vT);

  attn_kernel<<<dim3(512), blk, 0, stream>>>(qb, kb, vT, gate, attn);

  gemm256<1><<<dim3(16 * 16), dim3(512), 0, stream>>>(attn, woT, d_out, nullptr, nullptr, 16);
}

// Round 13
// 824.104 us; speedup vs baseline: 1.5203x; 1.0324x over previous
//
#include <hip/hip_runtime.h>
#include <hip/hip_bf16.h>
#include <cstdint>

typedef float  f32x4  __attribute__((ext_vector_type(4)));
typedef __bf16 bf16x8 __attribute__((ext_vector_type(8)));
typedef __bf16 bf16x4 __attribute__((ext_vector_type(4)));
typedef __bf16 bf16x2 __attribute__((ext_vector_type(2)));

#define AS1 __attribute__((address_space(1)))
#define AS3 __attribute__((address_space(3)))

static constexpr int D   = 4096;
static constexpr int SEQ = 2048;
static constexpr int MX  = 4224;   // padded rows: 4096 x-rows + 10 adapter + pad

__device__ __forceinline__ void gload_lds16(const void* g, void* l) {
  __builtin_amdgcn_global_load_lds((AS1 void*)(g), (AS3 void*)(l), 16, 0, 0);
}

__device__ __forceinline__ f32x4 mfma16(bf16x8 a, bf16x8 b, f32x4 c) {
  return __builtin_amdgcn_mfma_f32_16x16x32_bf16(a, b, c, 0, 0, 0);
}

// bijective XCD-chunked remap (m204)
__device__ __forceinline__ int xcd_chunk(int orig, int nwg) {
  int q = nwg >> 3, r = nwg & 7;
  int xcd = orig & 7, pos = orig >> 3;
  return (xcd < r ? xcd * (q + 1) : r * (q + 1) + (xcd - r) * q) + pos;
}

// barrier that is also a compiler memory fence
#define BARF() asm volatile("s_barrier" ::: "memory")

// ---------------------------------------------------------------------------
// transpose + cast x4: W[z] (f32, K x N row-major) -> WT base + z*D*D
// (bf16, N x K row-major). grid (64, 64, 4).
__global__ __launch_bounds__(256) void transpose_cast4(const float* __restrict__ w0,
                                                       const float* __restrict__ w1,
                                                       const float* __restrict__ w2,
                                                       const float* __restrict__ w3,
                                                       __bf16* __restrict__ WT) {
  __shared__ float tile[64][65];
  const float* W = (blockIdx.z == 0) ? w0 : (blockIdx.z == 1) ? w1
                 : (blockIdx.z == 2) ? w2 : w3;
  __bf16* dst = WT + (size_t)blockIdx.z * D * D;
  const int t  = threadIdx.x;
  const int r0 = blockIdx.x * 64;
  const int c0 = blockIdx.y * 64;
#pragma unroll
  for (int p = 0; p < 4; ++p) {
    int e = p * 1024 + t * 4;
    int row = e >> 6, col = e & 63;
    f32x4 v = *(const f32x4*)(W + (size_t)(r0 + row) * D + c0 + col);
#pragma unroll
    for (int i = 0; i < 4; ++i) tile[row][col + i] = v[i];
  }
  __syncthreads();
#pragma unroll
  for (int p = 0; p < 2; ++p) {
    int e = p * 2048 + t * 8;
    int orow = e >> 6, ocol = e & 63;
    bf16x8 o;
#pragma unroll
    for (int i = 0; i < 8; ++i) o[i] = (__bf16)tile[ocol + i][orow];
    *(bf16x8*)(dst + (size_t)(c0 + orow) * D + r0 + ocol) = o;
  }
}

// ---------------------------------------------------------------------------
// build xa (bf16, MX x D): rows 0..4095 = x, 4096..4105 = adapter, rest 0
__global__ __launch_bounds__(256) void build_xa(const float* __restrict__ x,
                                                const float* __restrict__ ad,
                                                __bf16* __restrict__ xa) {
  int idx = blockIdx.x * 256 + threadIdx.x;
  int e = idx * 4;
  int row = e >> 12, col = e & 4095;
  f32x4 v = {};
  if (row < 4096)      v = *(const f32x4*)(x + (size_t)row * D + col);
  else if (row < 4106) v = *(const f32x4*)(ad + (size_t)(row - 4096) * D + col);
  bf16x4 o;
#pragma unroll
  for (int i = 0; i < 4; ++i) o[i] = (__bf16)v[i];
  *(bf16x4*)(xa + (size_t)row * D + col) = o;
}

// ---------------------------------------------------------------------------
// 8-phase GEMM, never-drain pipeline (R12 loop, R13 fused epilogue).
// Loop: tile k stages {A.hi(k+1)@P0, B.hi(k+1)@P1, A.lo(k+2)@P2,
// B.lo(k+2)@P3}; waits vmcnt(8) at P0/P1 only; tile 63 peeled vmcnt(0).
// MODE 0 epilogue: q/k panels get RoPE fused on the f32 accumulator (pair
// (2m,2m+1) = adjacent lanes, one shfl_xor(1)); v panel stores TRANSPOSED
// to vT[(d)*MX + kv] as packed bf16x4. MODE 1: f32 out.
template <int MODE>
__global__ __launch_bounds__(512, 2) void gemm256(const __bf16* __restrict__ A,
                                                  const __bf16* __restrict__ BT,
                                                  void* __restrict__ O0,
                                                  void* __restrict__ O1,
                                                  void* __restrict__ O2,
                                                  const float* __restrict__ FC,
                                                  const float* __restrict__ FS,
                                                  int Mt) {
  __shared__ __bf16 lds[65536];   // [2 slot][A|B][2 half][128][8 ch][8]
  const int tid = threadIdx.x;
  const int wv = tid >> 6, ln = tid & 63;
  const int lg = ln >> 4, lr = ln & 15;

  const int nwg = gridDim.x;
  const int wgid = xcd_chunk(blockIdx.x, nwg);
  const int m0 = (wgid % Mt) * 256;
  const int n0 = (wgid / Mt) * 256;
  const int wm = (wv >> 2) * 128, wn = (wv & 3) * 64;

  auto stageHalf = [&](int k, int mat, int half) {
    const int slot = k & 1;
    const int kt = k * 64;
    const __bf16* base = mat ? BT + (size_t)(n0 + half * 128) * 4096
                             : A  + (size_t)(m0 + half * 128) * 4096;
#pragma unroll
    for (int i = 0; i < 2; ++i) {
      int c = i * 512 + tid;          // chunk 0..1023
      int r = c >> 3;                 // row-in-half 0..127
      int ch = (c & 7) ^ (r & 7);     // pre-swizzled source k-chunk
      gload_lds16(base + (size_t)r * 4096 + kt + ch * 8,
                  lds + slot * 32768 + mat * 16384 + half * 8192 +
                      (i * 512 + wv * 64) * 8);
    }
  };

  f32x4 acc[8][4] = {};
  bf16x8 aLo[4][2], aHi[4][2], bLo[2][2], bHi[2][2];

  auto rdA = [&](const __bf16* pA, int mi, int kk) -> bf16x8 {
    int r = wm + mi * 16 + lr;
    int R = r & 127;
    int cw = (kk * 4 + lg) ^ (R & 7);
    return *(const bf16x8*)(pA + (r >> 7) * 8192 + R * 64 + cw * 8);
  };
  auto rdB = [&](const __bf16* pB, int ni, int kk) -> bf16x8 {
    int n = wn + ni * 16 + lr;
    int R = n & 127;
    int cw = (kk * 4 + lg) ^ (R & 7);
    return *(const bf16x8*)(pB + (n >> 7) * 8192 + R * 64 + cw * 8);
  };

  // prologue: 6 half-tiles (12 loads outstanding)
  stageHalf(0, 0, 0);
  stageHalf(0, 1, 0);
  stageHalf(0, 0, 1);
  stageHalf(0, 1, 1);
  stageHalf(1, 0, 0);
  stageHalf(1, 1, 0);

  for (int k = 0; k < 63; ++k) {
    const int slot = k & 1;
    const __bf16* pA = lds + slot * 32768;
    const __bf16* pB = lds + slot * 32768 + 16384;

    // ---- P0: stage A.hi(k+1); vmcnt(8); quad LoLo
    stageHalf(k + 1, 0, 1);
    asm volatile("s_waitcnt vmcnt(8)" ::: "memory");
    BARF();
#pragma unroll
    for (int mi = 0; mi < 4; ++mi)
#pragma unroll
      for (int kk = 0; kk < 2; ++kk) aLo[mi][kk] = rdA(pA, mi, kk);
#pragma unroll
    for (int ni = 0; ni < 2; ++ni)
#pragma unroll
      for (int kk = 0; kk < 2; ++kk) bLo[ni][kk] = rdB(pB, ni, kk);
    __builtin_amdgcn_s_setprio(1);
#pragma unroll
    for (int kk = 0; kk < 2; ++kk)
#pragma unroll
      for (int mi = 0; mi < 4; ++mi)
#pragma unroll
        for (int ni = 0; ni < 2; ++ni)
          acc[mi][ni] = mfma16(aLo[mi][kk], bLo[ni][kk], acc[mi][ni]);
    __builtin_amdgcn_s_setprio(0);
    BARF();

    // ---- P1: stage B.hi(k+1); hoisted aHi reads; vmcnt(8)
    stageHalf(k + 1, 1, 1);
#pragma unroll
    for (int mi = 0; mi < 4; ++mi)
#pragma unroll
      for (int kk = 0; kk < 2; ++kk) aHi[mi][kk] = rdA(pA, mi + 4, kk);
    asm volatile("s_waitcnt vmcnt(8)" ::: "memory");
    BARF();
    __builtin_amdgcn_s_setprio(1);
#pragma unroll
    for (int kk = 0; kk < 2; ++kk)
#pragma unroll
      for (int mi = 0; mi < 4; ++mi)
#pragma unroll
        for (int ni = 0; ni < 2; ++ni)
          acc[mi + 4][ni] = mfma16(aHi[mi][kk], bLo[ni][kk], acc[mi + 4][ni]);
    __builtin_amdgcn_s_setprio(0);
    BARF();

    // ---- P2: stage A.lo(k+2); hoisted bHi reads; quad HiHi
    if (k + 2 < 64) stageHalf(k + 2, 0, 0);
#pragma unroll
    for (int ni = 0; ni < 2; ++ni)
#pragma unroll
      for (int kk = 0; kk < 2; ++kk) bHi[ni][kk] = rdB(pB, ni + 2, kk);
    BARF();
    __builtin_amdgcn_s_setprio(1);
#pragma unroll
    for (int kk = 0; kk < 2; ++kk)
#pragma unroll
      for (int mi = 0; mi < 4; ++mi)
#pragma unroll
        for (int ni = 0; ni < 2; ++ni)
          acc[mi + 4][ni + 2] = mfma16(aHi[mi][kk], bHi[ni][kk], acc[mi + 4][ni + 2]);
    __builtin_amdgcn_s_setprio(0);
    BARF();

    // ---- P3: stage B.lo(k+2); quad LoHi (aLo registers still valid)
    if (k + 2 < 64) stageHalf(k + 2, 1, 0);
    BARF();
    __builtin_amdgcn_s_setprio(1);
#pragma unroll
    for (int kk = 0; kk < 2; ++kk)
#pragma unroll
      for (int mi = 0; mi < 4; ++mi)
#pragma unroll
        for (int ni = 0; ni < 2; ++ni)
          acc[mi][ni + 2] = mfma16(aLo[mi][kk], bHi[ni][kk], acc[mi][ni + 2]);
    __builtin_amdgcn_s_setprio(0);
    BARF();
  }

  // ---- tile 63 peeled
  {
    const __bf16* pA = lds + (63 & 1) * 32768;
    const __bf16* pB = lds + (63 & 1) * 32768 + 16384;
    asm volatile("s_waitcnt vmcnt(0)" ::: "memory");
    BARF();
#pragma unroll
    for (int mi = 0; mi < 4; ++mi)
#pragma unroll
      for (int kk = 0; kk < 2; ++kk) aLo[mi][kk] = rdA(pA, mi, kk);
#pragma unroll
    for (int ni = 0; ni < 2; ++ni)
#pragma unroll
      for (int kk = 0; kk < 2; ++kk) bLo[ni][kk] = rdB(pB, ni, kk);
#pragma unroll
    for (int kk = 0; kk < 2; ++kk)
#pragma unroll
      for (int mi = 0; mi < 4; ++mi)
#pragma unroll
        for (int ni = 0; ni < 2; ++ni)
          acc[mi][ni] = mfma16(aLo[mi][kk], bLo[ni][kk], acc[mi][ni]);
#pragma unroll
    for (int mi = 0; mi < 4; ++mi)
#pragma unroll
      for (int kk = 0; kk < 2; ++kk) aHi[mi][kk] = rdA(pA, mi + 4, kk);
#pragma unroll
    for (int ni = 0; ni < 2; ++ni)
#pragma unroll
      for (int kk = 0; kk < 2; ++kk) bHi[ni][kk] = rdB(pB, ni + 2, kk);
#pragma unroll
    for (int kk = 0; kk < 2; ++kk)
#pragma unroll
      for (int mi = 0; mi < 4; ++mi)
#pragma unroll
        for (int ni = 0; ni < 2; ++ni) {
          acc[mi + 4][ni]     = mfma16(aHi[mi][kk], bLo[ni][kk], acc[mi + 4][ni]);
          acc[mi + 4][ni + 2] = mfma16(aHi[mi][kk], bHi[ni][kk], acc[mi + 4][ni + 2]);
          acc[mi][ni + 2]     = mfma16(aLo[mi][kk], bHi[ni][kk], acc[mi][ni + 2]);
        }
  }

  // ---- epilogue
  if constexpr (MODE == 0) {
    const int sel = n0 >> 12;                 // 0=q, 1=k, 2=v
    const int colb = n0 & 4095;
    if (sel < 2) {
      // q/k: fused RoPE on f32 acc, then bf16 store (row-major)
      __bf16* out = sel ? (__bf16*)O1 : (__bf16*)O0;
#pragma unroll
      for (int mi = 0; mi < 8; ++mi)
#pragma unroll
        for (int j = 0; j < 4; ++j) {
          int row = m0 + wm + mi * 16 + lg * 4 + j;
          int s = row & (SEQ - 1);
#pragma unroll
          for (int ni = 0; ni < 4; ++ni) {
            int col = colb + wn + ni * 16 + lr;
            int fi = (col & 127) >> 1;
            float c  = FC[s * 64 + fi];
            float sn = FS[s * 64 + fi];
            float v = acc[mi][ni][j];
            float p = __shfl_xor(v, 1);
            // even lane holds re, odd holds im:
            float o = (lr & 1) ? (p * sn + v * c) : (v * c - p * sn);
            out[(size_t)row * 4096 + col] = (__bf16)o;
          }
        }
    } else {
      // v: transposed store to vT[(d)*MX + kv], packed bf16x4 over j
      __bf16* vT = (__bf16*)O2;
#pragma unroll
      for (int mi = 0; mi < 8; ++mi) {
        int row0 = m0 + wm + mi * 16 + lg * 4;
#pragma unroll
        for (int ni = 0; ni < 4; ++ni) {
          int col = colb + wn + ni * 16 + lr;
          bf16x4 pk;
#pragma unroll
          for (int j = 0; j < 4; ++j) pk[j] = (__bf16)acc[mi][ni][j];
          *(bf16x4*)(vT + (size_t)col * MX + row0) = pk;
        }
      }
    }
  } else {
    float* out = (float*)O0;
#pragma unroll
    for (int mi = 0; mi < 8; ++mi)
#pragma unroll
      for (int ni = 0; ni < 4; ++ni)
#pragma unroll
        for (int j = 0; j < 4; ++j) {
          int row = m0 + wm + mi * 16 + lg * 4 + j;
          int col = n0 + wn + ni * 16 + lr;
          out[(size_t)row * 4096 + col] = acc[mi][ni][j];
        }
  }
}

// ---------------------------------------------------------------------------
// Adapter mini-GEMM: rows 4096..4111 = [adapter;pad] @ [wk|wv].
// K goes to kb rows (row-major, NO RoPE — adapter K is unrotated);
// V goes TRANSPOSED to vT[(d)*MX + row].
__global__ __launch_bounds__(256) void gemm_adapter(const __bf16* __restrict__ xa,
                                                    const __bf16* __restrict__ BT,
                                                    __bf16* __restrict__ kb,
                                                    __bf16* __restrict__ vT) {
  const int tid = threadIdx.x;
  const int wv = tid >> 6, ln = tid & 63;
  const int lg = ln >> 4, lr = ln & 15;
  const int col0 = blockIdx.x * 256 + wv * 64;
  f32x4 acc[4] = {};
  for (int kt = 0; kt < 4096; kt += 32) {
    bf16x8 a = *(const bf16x8*)(xa + (size_t)(4096 + lr) * 4096 + kt + lg * 8);
#pragma unroll
    for (int ni = 0; ni < 4; ++ni) {
      bf16x8 b = *(const bf16x8*)(BT + (size_t)(col0 + ni * 16 + lr) * 4096 +
                                  kt + lg * 8);
      acc[ni] = mfma16(a, b, acc[ni]);
    }
  }
#pragma unroll
  for (int ni = 0; ni < 4; ++ni)
#pragma unroll
    for (int j = 0; j < 4; ++j) {
      int row = 4096 + lg * 4 + j;
      int col = col0 + ni * 16 + lr;
      if (col < 4096) kb[(size_t)row * 4096 + col] = (__bf16)acc[ni][j];
      else            vT[(size_t)(col & 4095) * MX + row] = (__bf16)acc[ni][j];
    }
}

// ---------------------------------------------------------------------------
// Flash attention + adapter (unchanged from R12, which passed).
__global__ __launch_bounds__(256) void attn_kernel(const __bf16* __restrict__ Q,
                                                   const __bf16* __restrict__ K,
                                                   const __bf16* __restrict__ VT,
                                                   const float* __restrict__ gate,
                                                   __bf16* __restrict__ Out) {
  __shared__ __bf16 Ks[2][64 * 128];
  __shared__ __bf16 Vs[2][128 * 64];
  __shared__ __bf16 Ps[4][32 * 64];

  const int tid = threadIdx.x;
  const int wv = tid >> 6, ln = tid & 63;
  const int lg = ln >> 4, lr = ln & 15;

  const int wgid = xcd_chunk(blockIdx.x, 512);
  const int px = wgid & 7;
  const int hb = wgid >> 3;
  const int h = hb & 31, b = hb >> 5;

  const float scale = 0.08838834764831845f;
  const float g = tanhf(gate[h]);

  auto stage = [&](int t, int buf) {
    const int kv0 = t * 64;
#pragma unroll
    for (int j = 0; j < 4; ++j) {
      int c = wv * 256 + j * 64 + ln;
      int rk = c >> 4, sck = (c & 15) ^ (rk & 7);
      gload_lds16(K + (size_t)(b * SEQ + kv0 + rk) * D + h * 128 + sck * 8,
                  Ks[buf] + (wv * 256 + j * 64) * 8);
      int rv = c >> 3, scv = (c & 7) ^ (rv & 7);
      gload_lds16(VT + (size_t)(h * 128 + rv) * MX + b * SEQ + kv0 + scv * 8,
                  Vs[buf] + (wv * 256 + j * 64) * 8);
    }
  };

  auto run_supertile = [&](int qt) {
    const int q0 = qt * 128;
    const int qbase = b * SEQ + q0 + wv * 32;

    bf16x8 qf[2][4];
#pragma unroll
    for (int mi = 0; mi < 2; ++mi)
#pragma unroll
      for (int kd = 0; kd < 4; ++kd)
        qf[mi][kd] = *(const bf16x8*)(Q + (size_t)(qbase + mi * 16 + lr) * D +
                                      h * 128 + kd * 32 + lg * 8);

    f32x4 O[2][8] = {};
    float mI2[2], lI2[2];
#pragma unroll
    for (int mi = 0; mi < 2; ++mi) { mI2[mi] = -1e30f; lI2[mi] = 0.f; }

    const int ntiles = 2 * qt + 2;
    stage(0, 0);

    for (int t = 0; t < ntiles; ++t) {
      const int cur = t & 1;
      const int kv0 = t * 64;
      if (t + 1 < ntiles) {
        stage(t + 1, cur ^ 1);
        asm volatile("s_waitcnt vmcnt(8)" ::: "memory");
      } else {
        asm volatile("s_waitcnt vmcnt(0)" ::: "memory");
      }
      __builtin_amdgcn_s_barrier();
      __builtin_amdgcn_sched_barrier(0);

      f32x4 S[2][4] = {};
      __builtin_amdgcn_s_setprio(1);
#pragma unroll
      for (int kd = 0; kd < 4; ++kd) {
        bf16x8 kf[4];
#pragma unroll
        for (int nf = 0; nf < 4; ++nf) {
          int kr = nf * 16 + lr;
          kf[nf] = *(const bf16x8*)(Ks[cur] + kr * 128 +
                                    (((kd * 4 + lg) ^ (kr & 7)) * 8));
        }
#pragma unroll
        for (int mi = 0; mi < 2; ++mi)
#pragma unroll
          for (int nf = 0; nf < 4; ++nf)
            S[mi][nf] = mfma16(kf[nf], qf[mi][kd], S[mi][nf]);
      }
      __builtin_amdgcn_s_setprio(0);

      float r2[2]; int grew = 0;
#pragma unroll
      for (int mi = 0; mi < 2; ++mi) {
        const int qg = q0 + wv * 32 + mi * 16 + lr;
        float mo = mI2[mi];
        float mt = -3e38f;
#pragma unroll
        for (int nf = 0; nf < 4; ++nf)
#pragma unroll
          for (int j = 0; j < 4; ++j) {
            int kvg = kv0 + nf * 16 + lg * 4 + j;
            float s = S[mi][nf][j] * scale;
            s = (kvg > qg) ? -1e30f : s;
            S[mi][nf][j] = s;
            mt = fmaxf(mt, s);
          }
        mt = fmaxf(mt, __shfl_xor(mt, 16));
        mt = fmaxf(mt, __shfl_xor(mt, 32));
        float mn = fmaxf(mo, mt);
        float ps = 0.f;
#pragma unroll
        for (int nf = 0; nf < 4; ++nf)
#pragma unroll
          for (int j = 0; j < 4; ++j) {
            float p = __expf(S[mi][nf][j] - mn);
            S[mi][nf][j] = p;
            ps += p;
          }
        ps += __shfl_xor(ps, 16);
        ps += __shfl_xor(ps, 32);
        float r = __expf(mo - mn);
        lI2[mi] = lI2[mi] * r + ps;
        mI2[mi] = mn;
        r2[mi] = r;
        grew |= (mn > mo) ? 1 : 0;
      }
      if (__any(grew)) {
#pragma unroll
        for (int mi = 0; mi < 2; ++mi)
#pragma unroll
          for (int j = 0; j < 4; ++j) {
            float rj = __shfl(r2[mi], lg * 4 + j);
#pragma unroll
            for (int n = 0; n < 8; ++n) O[mi][n][j] *= rj;
          }
      }

      // P -> bf16x4 packed stores
#pragma unroll
      for (int mi = 0; mi < 2; ++mi) {
        int q = mi * 16 + lr;
#pragma unroll
        for (int nf = 0; nf < 4; ++nf) {
          int kv = nf * 16 + lg * 4;
          bf16x4 pk;
#pragma unroll
          for (int j = 0; j < 4; ++j) pk[j] = (__bf16)S[mi][nf][j];
          *(bf16x4*)(Ps[wv] + q * 64 + (((kv >> 3) ^ (q & 7)) * 8) + (kv & 7)) = pk;
        }
      }

      __builtin_amdgcn_s_setprio(1);
#pragma unroll
      for (int kkv = 0; kkv < 2; ++kkv) {
        bf16x8 pf[2];
#pragma unroll
        for (int mi = 0; mi < 2; ++mi) {
          int prw = mi * 16 + lr;
          pf[mi] = *(const bf16x8*)(Ps[wv] + prw * 64 +
                                    (((kkv * 4 + lg) ^ (prw & 7)) * 8));
        }
#pragma unroll
        for (int n = 0; n < 8; ++n) {
          int vr = n * 16 + lr;
          bf16x8 vf = *(const bf16x8*)(Vs[cur] + vr * 64 +
                                       (((kkv * 4 + lg) ^ (vr & 7)) * 8));
#pragma unroll
          for (int mi = 0; mi < 2; ++mi) O[mi][n] = mfma16(pf[mi], vf, O[mi][n]);
        }
      }
      __builtin_amdgcn_s_setprio(0);

      __builtin_amdgcn_s_barrier();
      __builtin_amdgcn_sched_barrier(0);
    }

#pragma unroll
    for (int mi = 0; mi < 2; ++mi) {
      float inv = 1.0f / lI2[mi];
#pragma unroll
      for (int j = 0; j < 4; ++j) {
        float invj = __shfl(inv, lg * 4 + j);
#pragma unroll
        for (int n = 0; n < 8; ++n) O[mi][n][j] *= invj;
      }
    }

    {
      f32x4 Sa[2] = {};
#pragma unroll
      for (int kd = 0; kd < 4; ++kd) {
        bf16x8 kfa = *(const bf16x8*)(K + (size_t)(2 * SEQ + lr) * D +
                                      h * 128 + kd * 32 + lg * 8);
#pragma unroll
        for (int mi = 0; mi < 2; ++mi) Sa[mi] = mfma16(kfa, qf[mi][kd], Sa[mi]);
      }
#pragma unroll
      for (int mi = 0; mi < 2; ++mi) {
        float mt = -3e38f;
#pragma unroll
        for (int j = 0; j < 4; ++j) {
          int kv = lg * 4 + j;
          float s = Sa[mi][j] * scale;
          s = (kv >= 10) ? -1e30f : s;
          Sa[mi][j] = s;
          mt = fmaxf(mt, s);
        }
        mt = fmaxf(mt, __shfl_xor(mt, 16));
        mt = fmaxf(mt, __shfl_xor(mt, 32));
        float ps = 0.f;
#pragma unroll
        for (int j = 0; j < 4; ++j) {
          float p = __expf(Sa[mi][j] - mt);
          Sa[mi][j] = p;
          ps += p;
        }
        ps += __shfl_xor(ps, 16);
        ps += __shfl_xor(ps, 32);
        float gs = g / ps;
        int q = mi * 16 + lr;
        int kv = lg * 4;
        bf16x4 pk, z = {};
#pragma unroll
        for (int j = 0; j < 4; ++j) pk[j] = (__bf16)(Sa[mi][j] * gs);
        *(bf16x4*)(Ps[wv] + q * 64 + (((kv >> 3) ^ (q & 7)) * 8) + (kv & 7)) = pk;
        int kv2 = 16 + kv;
        *(bf16x4*)(Ps[wv] + q * 64 + (((kv2 >> 3) ^ (q & 7)) * 8) + (kv2 & 7)) = z;
      }
      bf16x8 pfa[2];
#pragma unroll
      for (int mi = 0; mi < 2; ++mi) {
        int prw = mi * 16 + lr;
        pfa[mi] = *(const bf16x8*)(Ps[wv] + prw * 64 + ((lg ^ (prw & 7)) * 8));
      }
#pragma unroll
      for (int n = 0; n < 8; ++n) {
        bf16x8 vfa = *(const bf16x8*)(VT + (size_t)(h * 128 + n * 16 + lr) * MX +
                                      2 * SEQ + lg * 8);
#pragma unroll
        for (int mi = 0; mi < 2; ++mi) O[mi][n] = mfma16(pfa[mi], vfa, O[mi][n]);
      }
    }

#pragma unroll
    for (int mi = 0; mi < 2; ++mi)
#pragma unroll
      for (int n = 0; n < 8; ++n)
#pragma unroll
        for (int j = 0; j < 4; ++j)
          Out[(size_t)(qbase + mi * 16 + lg * 4 + j) * D + h * 128 + n * 16 + lr] =
              (__bf16)O[mi][n][j];
  };

  run_supertile(15 - px);
  run_supertile(px);
}

// ---------------------------------------------------------------------------
extern "C" void kernel_launch(void* const* d_in, const int* in_sizes, int n_in,
                              void* d_out, int out_size, void* d_ws, size_t ws_size,
                              hipStream_t stream) {
  const float* x    = (const float*)d_in[0];
  const float* wq   = (const float*)d_in[1];
  const float* wk   = (const float*)d_in[2];
  const float* wv   = (const float*)d_in[3];
  const float* wo   = (const float*)d_in[4];
  const float* gate = (const float*)d_in[5];
  const float* ad   = (const float*)d_in[6];
  const float* fc   = (const float*)d_in[7];
  const float* fs   = (const float*)d_in[8];

  const size_t WSZ = (size_t)D * D * 2;     // 33,554,432
  const size_t XSZ = (size_t)MX * D * 2;    // 34,603,008
  if (ws_size < 4 * WSZ + XSZ + WSZ + 3 * XSZ) return;  // 306,184,192 needed

  char* w = (char*)d_ws;
  size_t off = 0;
  auto alloc = [&](size_t sz) { void* p = w + off; off += sz; return p; };
  __bf16* wqT = (__bf16*)alloc(WSZ);   // wqT/wkT/wvT contiguous = fused 12288xK B^T
  __bf16* wkT = (__bf16*)alloc(WSZ);
  __bf16* wvT = (__bf16*)alloc(WSZ);
  __bf16* woT = (__bf16*)alloc(WSZ);
  __bf16* xa  = (__bf16*)alloc(XSZ);
  __bf16* qb  = (__bf16*)alloc(WSZ);
  __bf16* kb  = (__bf16*)alloc(XSZ);
  __bf16* vb  = (__bf16*)alloc(XSZ);   // scratch; used as attention output
  __bf16* vT  = (__bf16*)alloc(XSZ);
  __bf16* attn = vb;
  (void)wkT; (void)wvT;

  dim3 blk(256);
  transpose_cast4<<<dim3(64, 64, 4), blk, 0, stream>>>(wq, wk, wv, wo, wqT);
  build_xa<<<dim3(16896), blk, 0, stream>>>(x, ad, xa);

  // fused QKV GEMM (rope fused for q/k, transposed store for v):
  // 16 M-tiles x 48 N-tiles = 768 = 3x256.
  gemm256<0><<<dim3(16 * 48), dim3(512), 0, stream>>>(xa, wqT, qb, kb, vT,
                                                      fc, fs, 16);
  // adapter rows 4096..4111: K -> kb rows (no RoPE), V -> vT transposed.
  gemm_adapter<<<dim3(32), blk, 0, stream>>>(xa, wkT, kb, vT);

  attn_kernel<<<dim3(512), blk, 0, stream>>>(qb, kb, vT, gate, attn);

  gemm256<1><<<dim3(16 * 16), dim3(512), 0, stream>>>(attn, woT, d_out,
                                                      nullptr, nullptr,
                                                      nullptr, nullptr, 16);
}